// Round 14
// baseline (323.478 us; speedup 1.0000x reference)
//
#include <hip/hip_runtime.h>
#include <math.h>

// ---------------------------------------------------------------------------
// HDMOEM round 14: conv_mid reverted to r11-v2 (best known). NEW: all ViT GEMM
// weights pre-converted to bf16 with wsc folded (wcvt_all) + bf16-weight GEMM
// (mfma_linear_bw); runtime ws_size check with f32 fallback.
// B=4, C=4, H=W=64, E=4 experts/path, TOPK=2. Router masks all-True, ignored.
// ---------------------------------------------------------------------------

#define DEV_INLINE __device__ __forceinline__

typedef __attribute__((ext_vector_type(8))) short bf16x8;
typedef __attribute__((ext_vector_type(4))) float f32x4;

DEV_INLINE float mp_silu_f(float x) { return x / ((1.f + __expf(-x)) * 0.596f); }

DEV_INLINE unsigned short f2bf(float x) {
    unsigned u = __float_as_uint(x);
    unsigned r = (u + 0x7fffu + ((u >> 16) & 1u)) >> 16;
    return (unsigned short)r;
}
DEV_INLINE float bf2f(unsigned short u) { return __uint_as_float(((unsigned)u) << 16); }
DEV_INLINE float bflo(unsigned u) { return __uint_as_float(u << 16); }
DEV_INLINE float bfhi(unsigned u) { return __uint_as_float(u & 0xffff0000u); }

// ---------------------------------------------------------------------------
struct RsEnt { const float* w; float* o; int fan; int rowStart; };
struct RsTab { RsEnt e[23]; };

__global__ void rowscale_all_kernel(RsTab t) {
    int r = blockIdx.x;
    int ti = 0;
#pragma unroll
    for (int j = 1; j < 23; ++j)
        if (r >= t.e[j].rowStart) ti = j;
    const float* p = t.e[ti].w;
    int fan = t.e[ti].fan;
    int row = r - t.e[ti].rowStart;
    p += (size_t)row * fan;
    float s = 0.f;
    for (int i = threadIdx.x; i < fan; i += 256) { float v = p[i]; s += v * v; }
    __shared__ float red[256];
    red[threadIdx.x] = s;
    __syncthreads();
    for (int st = 128; st > 0; st >>= 1) {
        if (threadIdx.x < st) red[threadIdx.x] += red[threadIdx.x + st];
        __syncthreads();
    }
    if (threadIdx.x == 0) {
        float mean = red[0] / (float)fan;
        t.e[ti].o[row] = 1.f / sqrtf((mean + 1e-8f) * (float)fan);
    }
}

// ---- mid-conv weights: [e][oc][ic][3][3] f32 -> [e][icc6][tap9][oc192][ic32]
__global__ void wmid_cvt_kernel(const float* __restrict__ w, const float* __restrict__ wsc,
                                unsigned short* __restrict__ wt) {
    int i = blockIdx.x * 256 + threadIdx.x;
    if (i >= 4 * 9 * 192 * 192) return;
    int icl = i % 32;
    int t = i / 32;
    int oc = t % 192; t /= 192;
    int tap = t % 9; t /= 9;
    int icc = t % 6;
    int e = t / 6;
    int ic = icc * 32 + icl;
    wt[i] = f2bf(w[(((size_t)(e * 192 + oc) * 192 + ic) * 9) + tap] * wsc[e * 192 + oc]);
}

// ---- ViT weights f32 [4][N][K] -> bf16 (wsc folded). Table-driven, 4 elem/thd.
struct WcEnt { const float* w; const float* wsc; int N, K; long start, elems; };
struct WcTab { WcEnt e[6]; };

__global__ void wcvt_all_kernel(WcTab t, unsigned short* __restrict__ out, long total) {
    long g = ((long)blockIdx.x * 256 + threadIdx.x) * 4;
    if (g >= total) return;
    int ti = 0;
#pragma unroll
    for (int j = 1; j < 6; ++j)
        if (g >= t.e[j].start) ti = j;
    long local = g - t.e[ti].start;
    int K = t.e[ti].K;
    long nrow = local / K;                    // e*N + n
    float ws = t.e[ti].wsc[nrow];
    const float* src = t.e[ti].w + local;
    float4 v = *(const float4*)src;
    ushort4 r;
    r.x = f2bf(v.x * ws); r.y = f2bf(v.y * ws);
    r.z = f2bf(v.z * ws); r.w = f2bf(v.w * ws);
    *(ushort4*)&out[g] = r;
}

__global__ void femb_kernel(const float* __restrict__ tv, const float* __restrict__ fr,
                            const float* __restrict__ ph, float* __restrict__ femb) {
    int i = blockIdx.x * 256 + threadIdx.x;
    if (i >= 1024) return;
    int b = i >> 8, j = i & 255;
    femb[i] = 1.41421356237f * cosf(6.28318530717958647f * (tv[b] * fr[j] + ph[j]));
}

// ---- wave-per-output GEMV for small-M linears
template <int ACT, int HASRES>
__global__ void gemv_kernel(const float* __restrict__ A, const float* __restrict__ W,
                            const float* __restrict__ wsc, const float* __restrict__ res,
                            float osc, float* __restrict__ out, int N, int K) {
    int o = blockIdx.x * 4 + (threadIdx.x >> 6);
    int lane = threadIdx.x & 63;
    int m = o / N, n = o % N;
    const float* a = A + (size_t)m * K;
    const float* w = W + (size_t)n * K;
    float s = 0.f;
    for (int k = lane; k < K; k += 64) s += a[k] * w[k];
#pragma unroll
    for (int sh = 32; sh > 0; sh >>= 1) s += __shfl_xor(s, sh);
    if (lane == 0) {
        float val = s * wsc[n];
        if (ACT) val = mp_silu_f(val);
        if (HASRES) val = (val + res[(size_t)m * N + n]) * osc;
        out[(size_t)m * N + n] = val;
    }
}

// ---- two-source GEMV
__global__ void gemv2_kernel(const float* __restrict__ A1, const float* __restrict__ W1,
                             const float* __restrict__ s1v, int K1,
                             const float* __restrict__ A2, const float* __restrict__ W2,
                             const float* __restrict__ s2v, int K2,
                             float* __restrict__ out, int N) {
    int o = blockIdx.x * 4 + (threadIdx.x >> 6);
    int lane = threadIdx.x & 63;
    int m = o / N, n = o % N;
    const float* a1 = A1 + (size_t)m * K1;
    const float* w1 = W1 + (size_t)n * K1;
    float s1 = 0.f;
    for (int k = lane; k < K1; k += 64) s1 += a1[k] * w1[k];
    const float* a2 = A2 + (size_t)m * K2;
    const float* w2 = W2 + (size_t)n * K2;
    float s2 = 0.f;
    for (int k = lane; k < K2; k += 64) s2 += a2[k] * w2[k];
    float t = s1 * s1v[n] + s2 * s2v[n];
#pragma unroll
    for (int sh = 32; sh > 0; sh >>= 1) t += __shfl_xor(t, sh);
    if (lane == 0) out[(size_t)m * N + n] = t;
}

__global__ void scale_kernel(const float* __restrict__ temb, const float* __restrict__ w,
                             const float* __restrict__ wsc, const float* __restrict__ zeta,
                             float* __restrict__ scale2) {
    __shared__ float lg[8];
    int t = threadIdx.x;
    if (t < 8) {
        int b = t >> 1, o = t & 1;
        float s = 0.f;
        for (int k = 0; k < 512; ++k) s += temb[b * 512 + k] * w[o * 512 + k];
        lg[t] = s * wsc[o] / zeta[0];
    }
    __syncthreads();
    if (t < 4) {
        float a = lg[t * 2], b2 = lg[t * 2 + 1];
        float m = fmaxf(a, b2);
        float e0 = expf(a - m), e1 = expf(b2 - m);
        float inv = 2.f / (e0 + e1);
        scale2[t * 2] = e0 * inv;
        scale2[t * 2 + 1] = e1 * inv;
    }
}

__global__ void meanx_kernel(const float* __restrict__ x, float* __restrict__ mean_x) {
    int bc = blockIdx.x;
    float s = 0.f;
    for (int i = threadIdx.x; i < 4096; i += 256) s += x[bc * 4096 + i];
    __shared__ float red[256];
    red[threadIdx.x] = s;
    __syncthreads();
    for (int st = 128; st > 0; st >>= 1) {
        if (threadIdx.x < st) red[threadIdx.x] += red[threadIdx.x + st];
        __syncthreads();
    }
    if (threadIdx.x == 0) mean_x[bc] = red[0] * (1.f / 4096.f);
}

__global__ void router_kernel(const float* __restrict__ mean_x, const float* __restrict__ scale2,
                              const float* __restrict__ temb,
                              const float* __restrict__ wu, const float* __restrict__ su,
                              const float* __restrict__ wv, const float* __restrict__ sv,
                              const float* __restrict__ zeta,
                              int* __restrict__ eidx, float* __restrict__ gain,
                              float* __restrict__ rwv,
                              float* __restrict__ probs_out) {
    __shared__ float lg[2][4][4];
    int t = threadIdx.x;
    if (t < 32) {
        int r = t >> 4, b = (t >> 2) & 3, e = t & 3;
        const float* w = (r == 0) ? wu : wv;
        const float* sc = (r == 0) ? su : sv;
        float ps = scale2[b * 2 + (r == 0 ? 1 : 0)];
        float acc = 0.f;
        for (int c = 0; c < 4; ++c) acc += mean_x[b * 4 + c] * ps * w[e * 516 + c];
        for (int j = 0; j < 512; ++j) acc += temb[b * 512 + j] * w[e * 516 + 4 + j];
        lg[r][b][e] = acc * sc[e] / zeta[0];
    }
    __syncthreads();
    if (t < 8) {
        int r = t >> 2, b = t & 3;
        float p[4];
        float mx = -1e30f;
        for (int e = 0; e < 4; ++e) mx = fmaxf(mx, lg[r][b][e]);
        float sum = 0.f;
        for (int e = 0; e < 4; ++e) { p[e] = expf(lg[r][b][e] - mx); sum += p[e]; }
        for (int e = 0; e < 4; ++e) p[e] /= sum;
        int i1 = 0;
        for (int e = 1; e < 4; ++e) if (p[e] > p[i1]) i1 = e;
        int i2 = -1;
        for (int e = 0; e < 4; ++e) { if (e == i1) continue; if (i2 < 0 || p[e] > p[i2]) i2 = e; }
        float inv = 1.f / (p[i1] + p[i2]);
        if (r == 0) {
            eidx[b * 2] = i1; eidx[b * 2 + 1] = i2;
            gain[b * 2] = p[i1] * inv; gain[b * 2 + 1] = p[i2] * inv;
        } else {
            for (int e = 0; e < 4; ++e) rwv[b * 4 + e] = 0.f;
            rwv[b * 4 + i1] = p[i1] * inv;
            rwv[b * 4 + i2] = p[i2] * inv;
        }
        for (int e = 0; e < 4; ++e) probs_out[r * 16 + b * 4 + e] = p[e];
    }
}

__global__ void make_patch_kernel(const float* __restrict__ x, const float* __restrict__ scale2,
                                  float* __restrict__ in_unet, unsigned short* __restrict__ pt) {
    int i = blockIdx.x * 256 + threadIdx.x;
    if (i >= 65536) return;
    int b = i >> 14;
    int r = i & 16383;
    int s = r >> 8, f = r & 255;
    int c = f >> 6, py = (f >> 3) & 7, px = f & 7;
    int gy = s >> 3, gx = s & 7;
    int src = ((b * 4 + c) * 64 + gy * 8 + py) * 64 + gx * 8 + px;
    float v = x[src];
    pt[i] = f2bf(scale2[b * 2] * v);
    in_unet[src] = scale2[b * 2 + 1] * v;
}

__global__ void textp_kernel(const float* __restrict__ te, float* __restrict__ tp) {
    int i = blockIdx.x * 256 + threadIdx.x;
    if (i >= 3072) return;
    int b = i / 768, f = i % 768;
    float s = 0.f;
    for (int t = 0; t < 77; ++t) s += te[(size_t)(b * 77 + t) * 768 + f];
    tp[i] = s * (1.f / 77.f);
}

// ---------------------------------------------------------------------------
// conv_in (slots): NCHW f32 -> NHWC bf16 per slot. grid (16,24,8)
__global__ void conv_in_kernel(const float* __restrict__ in, const float* __restrict__ wbase,
                               const float* __restrict__ wscb, const float* __restrict__ tvec,
                               const int* __restrict__ eidx,
                               unsigned short* __restrict__ out) {
    int z = blockIdx.z, b = z >> 1;
    int e = eidx[z];
    const float* w = wbase + (size_t)e * 6912;
    const float* wsc = wscb + e * 192;
    const float* tmod = tvec + b * 768 + e * 192;
    int tileIdx = blockIdx.x;
    int ty0 = (tileIdx >> 2) * 16, tx0 = (tileIdx & 3) * 16;
    int oc0 = blockIdx.y * 8;
    int lty = threadIdx.x >> 4, ltx = threadIdx.x & 15;
    int y = ty0 + lty, x = tx0 + ltx;
    __shared__ float tile[4][18][18];
    for (int i = threadIdx.x; i < 4 * 18 * 18; i += 256) {
        int ic = i / 324, rr = (i / 18) % 18, cc = i % 18;
        int gy = ty0 - 1 + rr, gx = tx0 - 1 + cc;
        float v = 0.f;
        if (gy >= 0 && gy < 64 && gx >= 0 && gx < 64)
            v = in[((b * 4 + ic) * 64 + gy) * 64 + gx];
        tile[ic][rr][cc] = v;
    }
    __syncthreads();
    float win[4][9];
#pragma unroll
    for (int ic = 0; ic < 4; ++ic)
#pragma unroll
        for (int ky = 0; ky < 3; ++ky)
#pragma unroll
            for (int kx = 0; kx < 3; ++kx)
                win[ic][ky * 3 + kx] = tile[ic][lty + ky][ltx + kx];
#pragma unroll
    for (int o = 0; o < 8; ++o) {
        int oc = oc0 + o;
        float acc = 0.f;
#pragma unroll
        for (int ic = 0; ic < 4; ++ic) {
            const float* wp = w + (size_t)(oc * 4 + ic) * 9;
#pragma unroll
            for (int kk = 0; kk < 9; ++kk) acc += wp[kk] * win[ic][kk];
        }
        float val = acc * wsc[oc] * (1.f + tmod[oc]);
        val = mp_silu_f(val);
        out[((z * 64 + y) * 64 + x) * 192 + oc] = f2bf(val);
    }
}

// ---------------------------------------------------------------------------
// mid conv (r11-v2): 2 rows/block, per-icc weight prefetch, single-buffer LDS.
// wt layout [e][icc][tap][oc][ic32]. grid (32,3,8).
__global__ __launch_bounds__(256) void conv_mid_mfma(
    const unsigned short* __restrict__ in, const unsigned short* __restrict__ wtbase,
    const int* __restrict__ eidx,
    unsigned short* __restrict__ out) {
    int z = blockIdx.z;
    int e = eidx[z];
    const unsigned short* wt = wtbase + (size_t)e * 331776;
    int y0 = blockIdx.x * 2;
    int oc0 = blockIdx.y * 64;
    int wid = threadIdx.x >> 6, lane = threadIdx.x & 63;
    int wm = wid >> 1, wn = wid & 1;
    int l15 = lane & 15, lq = lane >> 4;

    __shared__ unsigned short Alds[4 * 66 * 72];
    f32x4 acc[4][2];
#pragma unroll
    for (int g = 0; g < 4; ++g)
#pragma unroll
        for (int f = 0; f < 2; ++f) acc[g][f] = (f32x4){0.f, 0.f, 0.f, 0.f};

    int ocA = oc0 + wn * 32 + l15;
    int ocB = ocA + 16;

    for (int icc = 0; icc < 6; ++icc) {
        const unsigned short* wicc = wt + (size_t)icc * (9 * 192 * 32);
        bf16x8 wreg[9][2];
#pragma unroll
        for (int tap = 0; tap < 9; ++tap) {
            wreg[tap][0] = *(const bf16x8*)&wicc[(tap * 192 + ocA) * 32 + 8 * lq];
            wreg[tap][1] = *(const bf16x8*)&wicc[(tap * 192 + ocB) * 32 + 8 * lq];
        }
        int ic0 = icc * 32;
        for (int i = threadIdx.x; i < 1056; i += 256) {
            int q = i & 3;
            int xx = (i >> 2) % 66;
            int r = (i >> 2) / 66;
            int y = y0 - 1 + r, xg = xx - 1;
            uint4 val = {0u, 0u, 0u, 0u};
            if (y >= 0 && y < 64 && xg >= 0 && xg < 64)
                val = *(const uint4*)&in[((z * 64 + y) * 64 + xg) * 192 + ic0 + q * 8];
            *(uint4*)&Alds[(r * 66 + xx) * 72 + q * 8] = val;
        }
        __syncthreads();
#pragma unroll
        for (int tap = 0; tap < 9; ++tap) {
            int ky = tap / 3, kx = tap % 3;
            int r = wm + ky;
#pragma unroll
            for (int g = 0; g < 4; ++g) {
                int xx = g * 16 + l15 + kx;
                bf16x8 afr = *(const bf16x8*)&Alds[(r * 66 + xx) * 72 + 8 * lq];
                acc[g][0] = __builtin_amdgcn_mfma_f32_16x16x32_bf16(afr, wreg[tap][0], acc[g][0], 0, 0, 0);
                acc[g][1] = __builtin_amdgcn_mfma_f32_16x16x32_bf16(afr, wreg[tap][1], acc[g][1], 0, 0, 0);
            }
        }
        __syncthreads();
    }
    int orow = y0 + wm;
#pragma unroll
    for (int g = 0; g < 4; ++g)
#pragma unroll
        for (int fn = 0; fn < 2; ++fn) {
            int oc = oc0 + wn * 32 + fn * 16 + l15;
#pragma unroll
            for (int r2 = 0; r2 < 4; ++r2) {
                int px = g * 16 + lq * 4 + r2;
                float v = mp_silu_f(acc[g][fn][r2]);
                out[((z * 64 + orow) * 64 + px) * 192 + oc] = f2bf(v);
            }
        }
}

// ---------------------------------------------------------------------------
// conv_out (slots, split-K): grid (16 tiles, 8 kchunks, 8 slots), atomicAdd.
__global__ __launch_bounds__(256) void conv_out_kernel(
    const unsigned short* __restrict__ in, const float* __restrict__ wbase,
    const float* __restrict__ wscb, const int* __restrict__ eidx,
    const float* __restrict__ gain, float* __restrict__ out) {
    int z = blockIdx.z, b = z >> 1;
    int e = eidx[z];
    float g = gain[z];
    const float* w = wbase + (size_t)e * 6912;
    const float* wsc = wscb + e * 4;
    int c0 = blockIdx.y * 24;
    int tileIdx = blockIdx.x;
    int ty0 = (tileIdx >> 2) * 16, tx0 = (tileIdx & 3) * 16;
    int lty = threadIdx.x >> 4, ltx = threadIdx.x & 15;
    int y = ty0 + lty, x = tx0 + ltx;
    __shared__ float tile[24][18][18];
    for (int i = threadIdx.x; i < 972; i += 256) {
        int q = i % 3, cell = i / 3;
        int rr = cell / 18, cc = cell % 18;
        int gy = ty0 - 1 + rr, gx = tx0 - 1 + cc;
        uint4 raw = {0u, 0u, 0u, 0u};
        if (gy >= 0 && gy < 64 && gx >= 0 && gx < 64)
            raw = *(const uint4*)&in[((z * 64 + gy) * 64 + gx) * 192 + c0 + q * 8];
        int icb = q * 8;
        tile[icb + 0][rr][cc] = bflo(raw.x);
        tile[icb + 1][rr][cc] = bfhi(raw.x);
        tile[icb + 2][rr][cc] = bflo(raw.y);
        tile[icb + 3][rr][cc] = bfhi(raw.y);
        tile[icb + 4][rr][cc] = bflo(raw.z);
        tile[icb + 5][rr][cc] = bfhi(raw.z);
        tile[icb + 6][rr][cc] = bflo(raw.w);
        tile[icb + 7][rr][cc] = bfhi(raw.w);
    }
    __syncthreads();
    float acc[4] = {0.f, 0.f, 0.f, 0.f};
#pragma unroll
    for (int ic = 0; ic < 24; ++ic) {
        float win[9];
#pragma unroll
        for (int ky = 0; ky < 3; ++ky)
#pragma unroll
            for (int kx = 0; kx < 3; ++kx)
                win[ky * 3 + kx] = tile[ic][lty + ky][ltx + kx];
#pragma unroll
        for (int o = 0; o < 4; ++o) {
            const float* wp = w + (size_t)(o * 192 + c0 + ic) * 9;
#pragma unroll
            for (int kk = 0; kk < 9; ++kk) acc[o] += wp[kk] * win[kk];
        }
    }
#pragma unroll
    for (int o = 0; o < 4; ++o)
        atomicAdd(&out[((b * 4 + o) * 64 + y) * 64 + x], g * acc[o] * wsc[o]);
}

// ---------------------------------------------------------------------------
// bf16 MFMA linear (f32 W fallback): grid (M/64, N/64, E), software pipelined.
template <int ACT>
__global__ __launch_bounds__(256) void mfma_linear_kernel(
    const unsigned short* __restrict__ A, int aE,
    const float* __restrict__ W, int wE,
    const float* __restrict__ wsc, int wscE,
    const float* __restrict__ pos, int posE,
    const float* __restrict__ cond, int condRow, int condE,
    const unsigned short* __restrict__ res, int resE, float outscale,
    const float* __restrict__ gate,
    unsigned short* __restrict__ outp, int outE,
    int M, int N, int K) {
    int e = blockIdx.z;
    int bm = blockIdx.x * 64, bn = blockIdx.y * 64;
    if (gate && gate[(bm >> 6) * 4 + e] == 0.f) return;
    A += (size_t)e * aE;
    W += (size_t)e * wE;
    wsc += (size_t)e * wscE;
    if (pos) pos += (size_t)e * posE;
    if (cond) cond += (size_t)e * condE;
    if (res) res += (size_t)e * resE;
    outp += (size_t)e * outE;

    int tid = threadIdx.x;
    int wid = tid >> 6, lane = tid & 63;
    int wm = wid >> 1, wn = wid & 1;
    int l15 = lane & 15, lq = lane >> 4;
    __shared__ unsigned short Al[64 * 72];
    __shared__ unsigned short Wl[64 * 72];
    f32x4 acc[2][2];
#pragma unroll
    for (int mf = 0; mf < 2; ++mf)
#pragma unroll
        for (int nf = 0; nf < 2; ++nf) acc[mf][nf] = (f32x4){0.f, 0.f, 0.f, 0.f};

    int ar = tid >> 3, ac = (tid & 7) * 8;
    int wr = tid >> 4, wc = (tid & 15) * 4;
    uint4 pa0, pa1;
    float4 pw0, pw1, pw2, pw3;

    auto gload = [&](int k0) {
        pa0 = *(const uint4*)&A[(size_t)(bm + ar) * K + k0 + ac];
        pa1 = *(const uint4*)&A[(size_t)(bm + ar + 32) * K + k0 + ac];
        pw0 = *(const float4*)&W[(size_t)(bn + wr) * K + k0 + wc];
        pw1 = *(const float4*)&W[(size_t)(bn + wr + 16) * K + k0 + wc];
        pw2 = *(const float4*)&W[(size_t)(bn + wr + 32) * K + k0 + wc];
        pw3 = *(const float4*)&W[(size_t)(bn + wr + 48) * K + k0 + wc];
    };
    auto sstore = [&]() {
        *(uint4*)&Al[ar * 72 + ac] = pa0;
        *(uint4*)&Al[(ar + 32) * 72 + ac] = pa1;
        ushort4 s;
        s.x = f2bf(pw0.x); s.y = f2bf(pw0.y); s.z = f2bf(pw0.z); s.w = f2bf(pw0.w);
        *(ushort4*)&Wl[wr * 72 + wc] = s;
        s.x = f2bf(pw1.x); s.y = f2bf(pw1.y); s.z = f2bf(pw1.z); s.w = f2bf(pw1.w);
        *(ushort4*)&Wl[(wr + 16) * 72 + wc] = s;
        s.x = f2bf(pw2.x); s.y = f2bf(pw2.y); s.z = f2bf(pw2.z); s.w = f2bf(pw2.w);
        *(ushort4*)&Wl[(wr + 32) * 72 + wc] = s;
        s.x = f2bf(pw3.x); s.y = f2bf(pw3.y); s.z = f2bf(pw3.z); s.w = f2bf(pw3.w);
        *(ushort4*)&Wl[(wr + 48) * 72 + wc] = s;
    };

    int nk = K >> 6;
    gload(0);
    for (int kk = 0; kk < nk; ++kk) {
        sstore();
        __syncthreads();
        if (kk + 1 < nk) gload((kk + 1) << 6);
#pragma unroll
        for (int ks = 0; ks < 2; ++ks) {
            bf16x8 af[2], wf[2];
#pragma unroll
            for (int mf = 0; mf < 2; ++mf)
                af[mf] = *(const bf16x8*)&Al[(wm * 32 + mf * 16 + l15) * 72 + ks * 32 + lq * 8];
#pragma unroll
            for (int nf = 0; nf < 2; ++nf)
                wf[nf] = *(const bf16x8*)&Wl[(wn * 32 + nf * 16 + l15) * 72 + ks * 32 + lq * 8];
#pragma unroll
            for (int mf = 0; mf < 2; ++mf)
#pragma unroll
                for (int nf = 0; nf < 2; ++nf)
                    acc[mf][nf] = __builtin_amdgcn_mfma_f32_16x16x32_bf16(af[mf], wf[nf], acc[mf][nf], 0, 0, 0);
        }
        __syncthreads();
    }
#pragma unroll
    for (int mf = 0; mf < 2; ++mf)
#pragma unroll
        for (int nf = 0; nf < 2; ++nf) {
            int n = bn + wn * 32 + nf * 16 + l15;
            float ws = wsc[n];
#pragma unroll
            for (int r = 0; r < 4; ++r) {
                int m = bm + wm * 32 + mf * 16 + lq * 4 + r;
                float val = acc[mf][nf][r] * ws;
                if (pos) val += pos[(m & 63) * N + n];
                if (cond) val *= (1.f + cond[(m >> 6) * condRow + n]);
                if (ACT) val = mp_silu_f(val);
                if (res) val = (val + bf2f(res[(size_t)m * N + n])) * outscale;
                outp[(size_t)m * N + n] = f2bf(val);
            }
        }
}

// ---------------------------------------------------------------------------
// bf16-weight MFMA linear (wsc pre-folded). W bf16 [4e][N][K].
template <int ACT>
__global__ __launch_bounds__(256) void mfma_linear_bw(
    const unsigned short* __restrict__ A, int aE,
    const unsigned short* __restrict__ W, long wE,
    const float* __restrict__ pos, int posE,
    const float* __restrict__ cond, int condRow, int condE,
    const unsigned short* __restrict__ res, int resE, float outscale,
    const float* __restrict__ gate,
    unsigned short* __restrict__ outp, int outE,
    int M, int N, int K) {
    int e = blockIdx.z;
    int bm = blockIdx.x * 64, bn = blockIdx.y * 64;
    if (gate && gate[(bm >> 6) * 4 + e] == 0.f) return;
    A += (size_t)e * aE;
    W += (size_t)e * wE;
    if (pos) pos += (size_t)e * posE;
    if (cond) cond += (size_t)e * condE;
    if (res) res += (size_t)e * resE;
    outp += (size_t)e * outE;

    int tid = threadIdx.x;
    int wid = tid >> 6, lane = tid & 63;
    int wm = wid >> 1, wn = wid & 1;
    int l15 = lane & 15, lq = lane >> 4;
    __shared__ unsigned short Al[64 * 72];
    __shared__ unsigned short Wl[64 * 72];
    f32x4 acc[2][2];
#pragma unroll
    for (int mf = 0; mf < 2; ++mf)
#pragma unroll
        for (int nf = 0; nf < 2; ++nf) acc[mf][nf] = (f32x4){0.f, 0.f, 0.f, 0.f};

    int ar = tid >> 3, ac = (tid & 7) * 8;     // rows ar, ar+32; 8 bf16 chunks
    uint4 pa0, pa1, pw0, pw1;

    auto gload = [&](int k0) {
        pa0 = *(const uint4*)&A[(size_t)(bm + ar) * K + k0 + ac];
        pa1 = *(const uint4*)&A[(size_t)(bm + ar + 32) * K + k0 + ac];
        pw0 = *(const uint4*)&W[(size_t)(bn + ar) * K + k0 + ac];
        pw1 = *(const uint4*)&W[(size_t)(bn + ar + 32) * K + k0 + ac];
    };
    auto sstore = [&]() {
        *(uint4*)&Al[ar * 72 + ac] = pa0;
        *(uint4*)&Al[(ar + 32) * 72 + ac] = pa1;
        *(uint4*)&Wl[ar * 72 + ac] = pw0;
        *(uint4*)&Wl[(ar + 32) * 72 + ac] = pw1;
    };

    int nk = K >> 6;
    gload(0);
    for (int kk = 0; kk < nk; ++kk) {
        sstore();
        __syncthreads();
        if (kk + 1 < nk) gload((kk + 1) << 6);
#pragma unroll
        for (int ks = 0; ks < 2; ++ks) {
            bf16x8 af[2], wf[2];
#pragma unroll
            for (int mf = 0; mf < 2; ++mf)
                af[mf] = *(const bf16x8*)&Al[(wm * 32 + mf * 16 + l15) * 72 + ks * 32 + lq * 8];
#pragma unroll
            for (int nf = 0; nf < 2; ++nf)
                wf[nf] = *(const bf16x8*)&Wl[(wn * 32 + nf * 16 + l15) * 72 + ks * 32 + lq * 8];
#pragma unroll
            for (int mf = 0; mf < 2; ++mf)
#pragma unroll
                for (int nf = 0; nf < 2; ++nf)
                    acc[mf][nf] = __builtin_amdgcn_mfma_f32_16x16x32_bf16(af[mf], wf[nf], acc[mf][nf], 0, 0, 0);
        }
        __syncthreads();
    }
#pragma unroll
    for (int mf = 0; mf < 2; ++mf)
#pragma unroll
        for (int nf = 0; nf < 2; ++nf) {
            int n = bn + wn * 32 + nf * 16 + l15;
#pragma unroll
            for (int r = 0; r < 4; ++r) {
                int m = bm + wm * 32 + mf * 16 + lq * 4 + r;
                float val = acc[mf][nf][r];
                if (pos) val += pos[(m & 63) * N + n];
                if (cond) val *= (1.f + cond[(m >> 6) * condRow + n]);
                if (ACT) val = mp_silu_f(val);
                if (res) val = (val + bf2f(res[(size_t)m * N + n])) * outscale;
                outp[(size_t)m * N + n] = f2bf(val);
            }
        }
}

// ---- ViT self-attention v2
__global__ __launch_bounds__(256) void vit_attn_kernel(
    const unsigned short* __restrict__ qkv_base,
    const float* __restrict__ rwv,
    unsigned short* __restrict__ out_base) {
    int e = blockIdx.x >> 5, b = (blockIdx.x >> 3) & 3, h = blockIdx.x & 7;
    if (rwv[b * 4 + e] == 0.f) return;
    const unsigned short* qkv = qkv_base + (size_t)e * 393216;
    unsigned short* out = out_base + (size_t)e * 131072;
    __shared__ float ks[64][68], vs[64][68];
    int tid = threadIdx.x;
    for (int i = tid; i < 512; i += 256) {
        int j = i >> 3, c = (i & 7) * 8;
        const unsigned short* kp = &qkv[(size_t)(b * 64 + j) * 1536 + 512 + h * 64 + c];
        uint4 kr = *(const uint4*)kp;
        uint4 vr = *(const uint4*)(kp + 512);
        float* kd = &ks[j][c];
        float* vd = &vs[j][c];
        kd[0] = bflo(kr.x); kd[1] = bfhi(kr.x); kd[2] = bflo(kr.y); kd[3] = bfhi(kr.y);
        kd[4] = bflo(kr.z); kd[5] = bfhi(kr.z); kd[6] = bflo(kr.w); kd[7] = bfhi(kr.w);
        vd[0] = bflo(vr.x); vd[1] = bfhi(vr.x); vd[2] = bflo(vr.y); vd[3] = bfhi(vr.y);
        vd[4] = bflo(vr.z); vd[5] = bfhi(vr.z); vd[6] = bflo(vr.w); vd[7] = bfhi(vr.w);
    }
    int qr = tid >> 2, kq = tid & 3;
    float qreg[64];
#pragma unroll
    for (int c8 = 0; c8 < 8; ++c8) {
        uint4 q4 = *(const uint4*)&qkv[(size_t)(b * 64 + qr) * 1536 + h * 64 + c8 * 8];
        qreg[c8 * 8 + 0] = bflo(q4.x); qreg[c8 * 8 + 1] = bfhi(q4.x);
        qreg[c8 * 8 + 2] = bflo(q4.y); qreg[c8 * 8 + 3] = bfhi(q4.y);
        qreg[c8 * 8 + 4] = bflo(q4.z); qreg[c8 * 8 + 5] = bfhi(q4.z);
        qreg[c8 * 8 + 6] = bflo(q4.w); qreg[c8 * 8 + 7] = bfhi(q4.w);
    }
    __syncthreads();
    float sc[16];
    float m = -1e30f;
    int j0 = kq * 16;
#pragma unroll
    for (int jj = 0; jj < 16; ++jj) {
        int j = j0 + jj;
        float s = 0.f;
#pragma unroll
        for (int d4 = 0; d4 < 16; ++d4) {
            float4 kk = *(const float4*)&ks[j][d4 * 4];
            s += qreg[d4 * 4] * kk.x + qreg[d4 * 4 + 1] * kk.y +
                 qreg[d4 * 4 + 2] * kk.z + qreg[d4 * 4 + 3] * kk.w;
        }
        s *= 0.125f;
        sc[jj] = s;
        m = fmaxf(m, s);
    }
    float l = 0.f;
    float4 acc4[16];
#pragma unroll
    for (int d4 = 0; d4 < 16; ++d4) acc4[d4] = (float4){0.f, 0.f, 0.f, 0.f};
#pragma unroll
    for (int jj = 0; jj < 16; ++jj) {
        int j = j0 + jj;
        float ee = __expf(sc[jj] - m);
        l += ee;
#pragma unroll
        for (int d4 = 0; d4 < 16; ++d4) {
            float4 vv = *(const float4*)&vs[j][d4 * 4];
            acc4[d4].x += ee * vv.x; acc4[d4].y += ee * vv.y;
            acc4[d4].z += ee * vv.z; acc4[d4].w += ee * vv.w;
        }
    }
#pragma unroll
    for (int mask = 1; mask <= 2; mask <<= 1) {
        float m2 = __shfl_xor(m, mask);
        float l2 = __shfl_xor(l, mask);
        float nm = fmaxf(m, m2);
        float c1 = __expf(m - nm), c2 = __expf(m2 - nm);
        l = l * c1 + l2 * c2;
#pragma unroll
        for (int d4 = 0; d4 < 16; ++d4) {
            acc4[d4].x = acc4[d4].x * c1 + __shfl_xor(acc4[d4].x, mask) * c2;
            acc4[d4].y = acc4[d4].y * c1 + __shfl_xor(acc4[d4].y, mask) * c2;
            acc4[d4].z = acc4[d4].z * c1 + __shfl_xor(acc4[d4].z, mask) * c2;
            acc4[d4].w = acc4[d4].w * c1 + __shfl_xor(acc4[d4].w, mask) * c2;
        }
        m = nm;
    }
    float inv = 1.f / l;
    unsigned short* op = &out[(size_t)(b * 64 + qr) * 512 + h * 64 + kq * 16];
#pragma unroll
    for (int d4 = 0; d4 < 4; ++d4) {
        int dd = kq * 4 + d4;
        ushort4 r;
        r.x = f2bf(acc4[dd].x * inv); r.y = f2bf(acc4[dd].y * inv);
        r.z = f2bf(acc4[dd].z * inv); r.w = f2bf(acc4[dd].w * inv);
        *(ushort4*)&op[d4 * 4] = r;
    }
}

__global__ void unpatch_scatter_kernel(const unsigned short* __restrict__ vout,
                                       const float* __restrict__ rwv,
                                       float* __restrict__ out_vit) {
    int i = blockIdx.x * 256 + threadIdx.x;
    if (i >= 65536) return;
    int b = i >> 14;
    int c = (i >> 12) & 3, y = (i >> 6) & 63, x = i & 63;
    int f = c * 64 + (y & 7) * 8 + (x & 7);
    int s = (y >> 3) * 8 + (x >> 3);
    int idx = (b * 64 + s) * 256 + f;
    float acc = 0.f;
#pragma unroll
    for (int e = 0; e < 4; ++e) {
        float g = rwv[b * 4 + e];
        if (g != 0.f) acc += g * bf2f(vout[e * 65536 + idx]);
    }
    out_vit[i] = acc;
}

// ---- ca_qkv + per-batch componentwise max|k|
__global__ void ca_qkv_kernel(const float* __restrict__ ou, const float* __restrict__ ov,
                              const float* __restrict__ wq, const float* __restrict__ sq,
                              const float* __restrict__ wk, const float* __restrict__ sk,
                              const float* __restrict__ wv, const float* __restrict__ sv,
                              float* __restrict__ q, float* __restrict__ kx, float* __restrict__ vx,
                              unsigned* __restrict__ kmax) {
    int i = blockIdx.x * 256 + threadIdx.x;
    if (i >= 16384) return;
    int b = i >> 12, t = i & 4095;
    float u[4], c[4];
#pragma unroll
    for (int cc = 0; cc < 4; ++cc) {
        u[cc] = ou[(size_t)(b * 4 + cc) * 4096 + t];
        c[cc] = ov[(size_t)(b * 4 + cc) * 4096 + t];
    }
    float km[4];
#pragma unroll
    for (int o = 0; o < 4; ++o) {
        float aq = 0.f, ak = 0.f, av = 0.f;
#pragma unroll
        for (int cc = 0; cc < 4; ++cc) {
            aq += wq[o * 4 + cc] * u[cc];
            ak += wk[o * 4 + cc] * c[cc];
            av += wv[o * 4 + cc] * c[cc];
        }
        float kvv = ak * sk[o];
        q[(size_t)(b * 4096 + t) * 4 + o] = aq * sq[o] * 0.5f;
        kx[(size_t)(b * 4096 + t) * 4 + o] = kvv;
        vx[(size_t)(b * 4096 + t) * 4 + o] = av * sv[o];
        km[o] = fabsf(kvv);
    }
#pragma unroll
    for (int sh = 32; sh > 0; sh >>= 1)
#pragma unroll
        for (int o = 0; o < 4; ++o) km[o] = fmaxf(km[o], __shfl_xor(km[o], sh));
    if ((threadIdx.x & 63) == 0)
#pragma unroll
        for (int o = 0; o < 4; ++o)
            atomicMax(&kmax[b * 4 + o], __float_as_uint(km[o]));
}

// ---- cross-attn v6: LDS-staged K/V, fixed-bound softmax.
__global__ __launch_bounds__(1024) void ca_attn_kernel(
    const float* __restrict__ q, const float* __restrict__ k,
    const float* __restrict__ v, const unsigned* __restrict__ kmax,
    float* __restrict__ o) {
    int b = blockIdx.x >> 6;
    int qg = blockIdx.x & 63;
    int lq = threadIdx.x & 63, wid = threadIdx.x >> 6;
    int qt = qg * 64 + lq;
    float4 qv = *(const float4*)&q[(size_t)(b * 4096 + qt) * 4];
    float M0 = __uint_as_float(kmax[b * 4 + 0]);
    float M1 = __uint_as_float(kmax[b * 4 + 1]);
    float M2 = __uint_as_float(kmax[b * 4 + 2]);
    float M3 = __uint_as_float(kmax[b * 4 + 3]);
    float nC = -(fabsf(qv.x) * M0 + fabsf(qv.y) * M1 + fabsf(qv.z) * M2 + fabsf(qv.w) * M3);
    const float4* kb = (const float4*)(k + (size_t)b * 16384);
    const float4* vb = (const float4*)(v + (size_t)b * 16384);

    __shared__ float4 kt[1024], vt[1024];
    int t = threadIdx.x;
    float l = 0.f, a0 = 0.f, a1 = 0.f, a2 = 0.f, a3 = 0.f;

    float4 pk = kb[t], pv = vb[t];
    int base = wid * 64;
    for (int r = 0; r < 4; ++r) {
        kt[t] = pk; vt[t] = pv;
        __syncthreads();
        if (r + 1 < 4) { pk = kb[(r + 1) * 1024 + t]; pv = vb[(r + 1) * 1024 + t]; }
#pragma unroll
        for (int jj = 0; jj < 64; jj += 4) {
            float4 kk0 = kt[base + jj],     kk1 = kt[base + jj + 1];
            float4 kk2 = kt[base + jj + 2], kk3 = kt[base + jj + 3];
            float4 vv0 = vt[base + jj],     vv1 = vt[base + jj + 1];
            float4 vv2 = vt[base + jj + 2], vv3 = vt[base + jj + 3];
            float s0 = fmaf(qv.w, kk0.w, fmaf(qv.z, kk0.z, fmaf(qv.y, kk0.y, fmaf(qv.x, kk0.x, nC))));
            float s1 = fmaf(qv.w, kk1.w, fmaf(qv.z, kk1.z, fmaf(qv.y, kk1.y, fmaf(qv.x, kk1.x, nC))));
            float s2 = fmaf(qv.w, kk2.w, fmaf(qv.z, kk2.z, fmaf(qv.y, kk2.y, fmaf(qv.x, kk2.x, nC))));
            float s3 = fmaf(qv.w, kk3.w, fmaf(qv.z, kk3.z, fmaf(qv.y, kk3.y, fmaf(qv.x, kk3.x, nC))));
            float e0 = __expf(s0), e1 = __expf(s1), e2 = __expf(s2), e3 = __expf(s3);
            l += (e0 + e1) + (e2 + e3);
            a0 = fmaf(e0, vv0.x, a0); a1 = fmaf(e0, vv0.y, a1);
            a2 = fmaf(e0, vv0.z, a2); a3 = fmaf(e0, vv0.w, a3);
            a0 = fmaf(e1, vv1.x, a0); a1 = fmaf(e1, vv1.y, a1);
            a2 = fmaf(e1, vv1.z, a2); a3 = fmaf(e1, vv1.w, a3);
            a0 = fmaf(e2, vv2.x, a0); a1 = fmaf(e2, vv2.y, a1);
            a2 = fmaf(e2, vv2.z, a2); a3 = fmaf(e2, vv2.w, a3);
            a0 = fmaf(e3, vv3.x, a0); a1 = fmaf(e3, vv3.y, a1);
            a2 = fmaf(e3, vv3.z, a2); a3 = fmaf(e3, vv3.w, a3);
        }
        __syncthreads();
    }
    __shared__ float red[16][64][5];
    red[wid][lq][0] = l;
    red[wid][lq][1] = a0; red[wid][lq][2] = a1;
    red[wid][lq][3] = a2; red[wid][lq][4] = a3;
    __syncthreads();
    if (threadIdx.x < 64) {
        int qq = threadIdx.x;
        float ll = 0.f, b0 = 0.f, b1 = 0.f, b2 = 0.f, b3 = 0.f;
#pragma unroll
        for (int s2 = 0; s2 < 16; ++s2) {
            ll += red[s2][qq][0];
            b0 += red[s2][qq][1];
            b1 += red[s2][qq][2];
            b2 += red[s2][qq][3];
            b3 += red[s2][qq][4];
        }
        float inv = 1.f / ll;
        float* op = &o[(size_t)(b * 4096 + qg * 64 + qq) * 4];
        op[0] = b0 * inv; op[1] = b1 * inv; op[2] = b2 * inv; op[3] = b3 * inv;
    }
}

// ---- fused: out-proj + balanced blend + gated combine -> d_out
__global__ void ca_final_kernel(const float* __restrict__ ao, const float* __restrict__ ou,
                                const float* __restrict__ wo, const float* __restrict__ so,
                                const float* __restrict__ gw1, const float* __restrict__ s1,
                                const float* __restrict__ gw2, const float* __restrict__ s2,
                                float* __restrict__ out) {
    int i = blockIdx.x * 256 + threadIdx.x;
    if (i >= 16384) return;
    int b = i >> 12, t = i & 4095;
    float oo[4], u[4], a[4];
#pragma unroll
    for (int j = 0; j < 4; ++j) oo[j] = ao[(size_t)(b * 4096 + t) * 4 + j];
#pragma unroll
    for (int c = 0; c < 4; ++c) u[c] = ou[(size_t)(b * 4 + c) * 4096 + t];
    const float binv = 1.21267812518f;
#pragma unroll
    for (int c = 0; c < 4; ++c) {
        float s = 0.f;
#pragma unroll
        for (int j = 0; j < 4; ++j) s += wo[c * 4 + j] * oo[j];
        s *= so[c];
        a[c] = (0.2f * u[c] + 0.8f * s) * binv;
    }
    float mvec[4];
#pragma unroll
    for (int o = 0; o < 4; ++o) {
        float s = 0.f;
#pragma unroll
        for (int c = 0; c < 4; ++c) s += gw1[o * 8 + c] * u[c] + gw1[o * 8 + 4 + c] * a[c];
        mvec[o] = mp_silu_f(s * s1[o]);
    }
    float g0 = 0.f, g1 = 0.f;
#pragma unroll
    for (int o = 0; o < 4; ++o) { g0 += gw2[o] * mvec[o]; g1 += gw2[4 + o] * mvec[o]; }
    g0 *= s2[0]; g1 *= s2[1];
    float mx = fmaxf(g0, g1);
    float e0 = expf(g0 - mx), e1 = expf(g1 - mx);
    float invd = 1.f / (e0 + e1);
    g0 = e0 * invd; g1 = e1 * invd;
#pragma unroll
    for (int c = 0; c < 4; ++c)
        out[(size_t)(b * 4 + c) * 4096 + t] = g0 * u[c] + g1 * a[c];
}

// ---------------------------------------------------------------------------
extern "C" void kernel_launch(void* const* d_in, const int* in_sizes, int n_in,
                              void* d_out, int out_size, void* d_ws, size_t ws_size,
                              hipStream_t stream) {
    (void)in_sizes; (void)n_in; (void)out_size;

    const float* x        = (const float*)d_in[0];
    const float* time_vec = (const float*)d_in[1];
    const float* text_emb = (const float*)d_in[2];
    const float* zeta     = (const float*)d_in[5];
    const float* f_freq   = (const float*)d_in[6];
    const float* f_phase  = (const float*)d_in[7];
    const float* w_f1     = (const float*)d_in[8];
    const float* w_f2     = (const float*)d_in[9];
    const float* w_scale  = (const float*)d_in[10];
    const float* w_ru     = (const float*)d_in[11];
    const float* w_rv     = (const float*)d_in[12];
    const float* uw_in    = (const float*)d_in[13];
    const float* uw_time  = (const float*)d_in[14];
    const float* uw_mid   = (const float*)d_in[15];
    const float* uw_out   = (const float*)d_in[16];
    const float* vw_patch = (const float*)d_in[17];
    const float* v_pos    = (const float*)d_in[18];
    const float* vw_qkv   = (const float*)d_in[19];
    const float* vw_proj  = (const float*)d_in[20];
    const float* vw_time  = (const float*)d_in[21];
    const float* vw_text  = (const float*)d_in[22];
    const float* vw_mlp1  = (const float*)d_in[23];
    const float* vw_mlp2  = (const float*)d_in[24];
    const float* vw_unp   = (const float*)d_in[25];
    const float* ca_wq    = (const float*)d_in[26];
    const float* ca_wk    = (const float*)d_in[27];
    const float* ca_wv    = (const float*)d_in[28];
    const float* ca_wo    = (const float*)d_in[29];
    const float* gw1      = (const float*)d_in[30];
    const float* gw2      = (const float*)d_in[31];

    float* out = (float*)d_out;

    float* Wp = (float*)d_ws;
    size_t off = 0;
    auto alloc = [&](size_t n) { float* p = Wp + off; off += (n + 3) & ~(size_t)3; return p; };

    float* s_wf1   = alloc(1024);
    float* s_wf2   = alloc(512);
    float* s_wsc   = alloc(2);
    float* s_wru   = alloc(4);
    float* s_wrv   = alloc(4);
    float* s_uwin  = alloc(768);
    float* s_uwt   = alloc(768);
    float* s_uwm   = alloc(768);
    float* s_uwo   = alloc(16);
    float* s_vwp   = alloc(2048);
    float* s_vwqkv = alloc(6144);
    float* s_vwpr  = alloc(2048);
    float* s_vwti  = alloc(2048);
    float* s_vwte  = alloc(2048);
    float* s_vwm1  = alloc(8192);
    float* s_vwm2  = alloc(2048);
    float* s_vwun  = alloc(1024);
    float* s_cawq  = alloc(4);
    float* s_cawk  = alloc(4);
    float* s_cawv  = alloc(4);
    float* s_cawo  = alloc(4);
    float* s_gw1   = alloc(4);
    float* s_gw2   = alloc(2);

    float* femb    = alloc(1024);
    float* h1      = alloc(4096);
    float* temb    = alloc(2048);
    float* scale2  = alloc(8);
    float* mean_x  = alloc(16);
    int*   eidx    = (int*)alloc(8);
    float* gain    = alloc(8);
    float* rwv     = alloc(16);
    float* textp   = alloc(3072);
    float* tvec    = alloc(3072);
    unsigned short* patchtok = (unsigned short*)alloc(32768);
    float* in_unet = alloc(65536);
    float* out_unet= alloc(65536);
    float* out_vit = alloc(65536);
    float* vcond   = alloc(8192);
    unsigned* kmax = (unsigned*)alloc(16);
    unsigned short* wtmid = (unsigned short*)alloc(663552);

    float* region  = alloc(6291456);
    unsigned short* bufA = (unsigned short*)region;
    unsigned short* bufB = (unsigned short*)(region + 3145728);
    unsigned short* us   = (unsigned short*)region;
    unsigned short* vtok  = us + 0;
    unsigned short* vqkv  = us + 524288;
    unsigned short* vao   = us + 2097152;
    unsigned short* vtok2 = us + 2621440;
    unsigned short* vhid  = us + 3145728;
    unsigned short* vtok3 = us + 5242880;
    unsigned short* vout  = us + 5767168;

    float* caq     = alloc(65536);
    float* cak     = alloc(65536);
    float* cav     = alloc(65536);
    float* cao     = alloc(65536);

    // ---- optional bf16 weight cache (wsc folded). u16 offsets within wbf:
    //   patch 0 / qkv 524288 / proj 3670016 / mlp1 4718592 / mlp2 8912896 / unp 13107200
    const long WBF_TOTAL = 13631488;   // u16 elems
    unsigned short* wbf = (unsigned short*)alloc(WBF_TOTAL / 2 + 4);
    bool useBf = ((size_t)off * sizeof(float) <= ws_size);

    // ---- merged rowscale
    RsTab tab;
    int rowCounts[23] = {1024, 512, 2, 4, 4, 768, 768, 768, 16, 2048, 6144, 2048,
                         2048, 2048, 8192, 2048, 1024, 4, 4, 4, 4, 4, 2};
    const float* srcs[23] = {w_f1, w_f2, w_scale, w_ru, w_rv, uw_in, uw_time, uw_mid, uw_out,
                             vw_patch, vw_qkv, vw_proj, vw_time, vw_text, vw_mlp1, vw_mlp2,
                             vw_unp, ca_wq, ca_wk, ca_wv, ca_wo, gw1, gw2};
    float* dsts[23] = {s_wf1, s_wf2, s_wsc, s_wru, s_wrv, s_uwin, s_uwt, s_uwm, s_uwo,
                       s_vwp, s_vwqkv, s_vwpr, s_vwti, s_vwte, s_vwm1, s_vwm2,
                       s_vwun, s_cawq, s_cawk, s_cawv, s_cawo, s_gw1, s_gw2};
    int fans[23] = {256, 1024, 512, 516, 516, 36, 512, 1728, 1728, 256, 512, 512,
                    512, 768, 512, 2048, 512, 4, 4, 4, 4, 8, 4};
    int cum = 0;
    for (int i = 0; i < 23; ++i) {
        tab.e[i].w = srcs[i]; tab.e[i].o = dsts[i];
        tab.e[i].fan = fans[i]; tab.e[i].rowStart = cum;
        cum += rowCounts[i];
    }
    rowscale_all_kernel<<<dim3(cum), dim3(256), 0, stream>>>(tab);
    wmid_cvt_kernel<<<dim3((1327104 + 255) / 256), dim3(256), 0, stream>>>(uw_mid, s_uwm, wtmid);

    if (useBf) {
        WcTab wt;
        wt.e[0] = {vw_patch, s_vwp, 512, 256, 0L, 524288L};
        wt.e[1] = {vw_qkv,  s_vwqkv, 1536, 512, 524288L, 3145728L};
        wt.e[2] = {vw_proj, s_vwpr, 512, 512, 3670016L, 1048576L};
        wt.e[3] = {vw_mlp1, s_vwm1, 2048, 512, 4718592L, 4194304L};
        wt.e[4] = {vw_mlp2, s_vwm2, 512, 2048, 8912896L, 4194304L};
        wt.e[5] = {vw_unp,  s_vwun, 256, 512, 13107200L, 524288L};
        wcvt_all_kernel<<<dim3((unsigned)((WBF_TOTAL / 4 + 255) / 256)), dim3(256), 0, stream>>>(
            wt, wbf, WBF_TOTAL);
    }

    auto gemv = [&](int ACT, int HASRES, const float* A, const float* W2, const float* wsc,
                    const float* res, float osc, float* o, int M, int N, int K) {
        dim3 g(M * N / 4);
        if (ACT)
            gemv_kernel<1, 0><<<g, 256, 0, stream>>>(A, W2, wsc, res, osc, o, N, K);
        else if (HASRES)
            gemv_kernel<0, 1><<<g, 256, 0, stream>>>(A, W2, wsc, res, osc, o, N, K);
        else
            gemv_kernel<0, 0><<<g, 256, 0, stream>>>(A, W2, wsc, res, osc, o, N, K);
    };

    // ---- time embedding chain
    femb_kernel<<<dim3(4), dim3(256), 0, stream>>>(time_vec, f_freq, f_phase, femb);
    gemv(1, 0, femb, w_f1, s_wf1, nullptr, 1.f, h1, 4, 1024, 256);
    gemv(0, 0, h1, w_f2, s_wf2, nullptr, 1.f, temb, 4, 512, 1024);

    scale_kernel<<<dim3(1), dim3(64), 0, stream>>>(temb, w_scale, s_wsc, zeta, scale2);
    meanx_kernel<<<dim3(16), dim3(256), 0, stream>>>(x, mean_x);
    router_kernel<<<dim3(1), dim3(64), 0, stream>>>(mean_x, scale2, temb, w_ru, s_wru, w_rv, s_wrv,
                                                    zeta, eidx, gain, rwv, out + 65536);
    make_patch_kernel<<<dim3(256), dim3(256), 0, stream>>>(x, scale2, in_unet, patchtok);
    textp_kernel<<<dim3(12), dim3(256), 0, stream>>>(text_emb, textp);

    gemv(0, 0, temb, uw_time, s_uwt, nullptr, 1.f, tvec, 4, 768, 512);

    hipMemsetAsync(out_unet, 0, 65536 * sizeof(float), stream);
    hipMemsetAsync(kmax, 0, 16 * sizeof(unsigned), stream);

    // ---- UNet conv chain, slot-compacted
    conv_in_kernel<<<dim3(16, 24, 8), dim3(256), 0, stream>>>(
        in_unet, uw_in, s_uwin, tvec, eidx, bufA);
    conv_mid_mfma<<<dim3(32, 3, 8), dim3(256), 0, stream>>>(
        bufA, wtmid, eidx, bufB);
    conv_out_kernel<<<dim3(16, 8, 8), dim3(256), 0, stream>>>(
        bufB, uw_out, s_uwo, eidx, gain, out_unet);

    // ---- ViT cond vectors
    gemv2_kernel<<<dim3(2048), dim3(256), 0, stream>>>(temb, vw_time, s_vwti, 512,
                                                       textp, vw_text, s_vwte, 768,
                                                       vcond, 2048);

    auto mlin = [&](int ACT, const unsigned short* A, int aE, const float* W2, int wE2,
                    const float* wsc, int wscE, const float* pos, int posE,
                    const float* cond, int condRow, int condE,
                    const unsigned short* res, int resE, float osc,
                    const float* gate, unsigned short* o, int outE, int M, int N, int K) {
        dim3 g(M / 64, N / 64, 4);
        if (ACT)
            mfma_linear_kernel<1><<<g, 256, 0, stream>>>(A, aE, W2, wE2, wsc, wscE, pos, posE,
                                                         cond, condRow, condE, res, resE, osc,
                                                         gate, o, outE, M, N, K);
        else
            mfma_linear_kernel<0><<<g, 256, 0, stream>>>(A, aE, W2, wE2, wsc, wscE, pos, posE,
                                                         cond, condRow, condE, res, resE, osc,
                                                         gate, o, outE, M, N, K);
    };
    auto mlinB = [&](int ACT, const unsigned short* A, int aE, const unsigned short* W2, long wE2,
                     const float* pos, int posE,
                     const float* cond, int condRow, int condE,
                     const unsigned short* res, int resE, float osc,
                     const float* gate, unsigned short* o, int outE, int M, int N, int K) {
        dim3 g(M / 64, N / 64, 4);
        if (ACT)
            mfma_linear_bw<1><<<g, 256, 0, stream>>>(A, aE, W2, wE2, pos, posE,
                                                     cond, condRow, condE, res, resE, osc,
                                                     gate, o, outE, M, N, K);
        else
            mfma_linear_bw<0><<<g, 256, 0, stream>>>(A, aE, W2, wE2, pos, posE,
                                                     cond, condRow, condE, res, resE, osc,
                                                     gate, o, outE, M, N, K);
    };

    // ---- ViT expert stack
    if (useBf) {
        mlinB(0, patchtok, 0, wbf + 0L, 131072L, v_pos, 32768,
              vcond, 2048, 512, nullptr, 0, 1.f, rwv, vtok, 131072, 256, 512, 256);
        mlinB(0, vtok, 131072, wbf + 524288L, 786432L, nullptr, 0,
              nullptr, 0, 0, nullptr, 0, 1.f, rwv, vqkv, 393216, 256, 1536, 512);
        vit_attn_kernel<<<dim3(128), dim3(256), 0, stream>>>(vqkv, rwv, vao);
        mlinB(0, vao, 131072, wbf + 3670016L, 262144L, nullptr, 0,
              nullptr, 0, 0, vtok, 131072, 0.70710678f, rwv, vtok2, 131072, 256, 512, 512);
        mlinB(1, vtok2, 131072, wbf + 4718592L, 1048576L, nullptr, 0,
              nullptr, 0, 0, nullptr, 0, 1.f, rwv, vhid, 524288, 256, 2048, 512);
        mlinB(0, vhid, 524288, wbf + 8912896L, 1048576L, nullptr, 0,
              nullptr, 0, 0, vtok2, 131072, 0.70710678f, rwv, vtok3, 131072, 256, 512, 2048);
        mlinB(0, vtok3, 131072, wbf + 13107200L, 131072L, nullptr, 0,
              nullptr, 0, 0, nullptr, 0, 1.f, rwv, vout, 65536, 256, 256, 512);
    } else {
        mlin(0, patchtok, 0, vw_patch, 131072, s_vwp, 512, v_pos, 32768,
             vcond, 2048, 512, nullptr, 0, 1.f, rwv, vtok, 131072, 256, 512, 256);
        mlin(0, vtok, 131072, vw_qkv, 786432, s_vwqkv, 1536, nullptr, 0,
             nullptr, 0, 0, nullptr, 0, 1.f, rwv, vqkv, 393216, 256, 1536, 512);
        vit_attn_kernel<<<dim3(128), dim3(256), 0, stream>>>(vqkv, rwv, vao);
        mlin(0, vao, 131072, vw_proj, 262144, s_vwpr, 512, nullptr, 0,
             nullptr, 0, 0, vtok, 131072, 0.70710678f, rwv, vtok2, 131072, 256, 512, 512);
        mlin(1, vtok2, 131072, vw_mlp1, 1048576, s_vwm1, 2048, nullptr, 0,
             nullptr, 0, 0, nullptr, 0, 1.f, rwv, vhid, 524288, 256, 2048, 512);
        mlin(0, vhid, 524288, vw_mlp2, 1048576, s_vwm2, 512, nullptr, 0,
             nullptr, 0, 0, vtok2, 131072, 0.70710678f, rwv, vtok3, 131072, 256, 512, 2048);
        mlin(0, vtok3, 131072, vw_unp, 131072, s_vwun, 256, nullptr, 0,
             nullptr, 0, 0, nullptr, 0, 1.f, rwv, vout, 65536, 256, 256, 512);
    }
    unpatch_scatter_kernel<<<dim3(256), dim3(256), 0, stream>>>(vout, rwv, out_vit);

    // ---- cross attention + fused tail
    ca_qkv_kernel<<<dim3(64), dim3(256), 0, stream>>>(out_unet, out_vit, ca_wq, s_cawq,
                                                      ca_wk, s_cawk, ca_wv, s_cawv,
                                                      caq, cak, cav, kmax);
    ca_attn_kernel<<<dim3(256), dim3(1024), 0, stream>>>(caq, cak, cav, kmax, cao);
    ca_final_kernel<<<dim3(64), dim3(256), 0, stream>>>(cao, out_unet, ca_wo, s_cawo,
                                                        gw1, s_gw1, gw2, s_gw2, out);
}

// Round 15
// 318.483 us; speedup vs baseline: 1.0157x; 1.0157x over previous
//
#include <hip/hip_runtime.h>
#include <math.h>

// ---------------------------------------------------------------------------
// HDMOEM round 15: round-12 best build (319.5us) + XCD-aware 1D swizzle for
// conv_mid (slot = blockid % 8 -> per-XCD L2 weight locality).
// B=4, C=4, H=W=64, E=4 experts/path, TOPK=2. Router masks all-True, ignored.
// ---------------------------------------------------------------------------

#define DEV_INLINE __device__ __forceinline__

typedef __attribute__((ext_vector_type(8))) short bf16x8;
typedef __attribute__((ext_vector_type(4))) float f32x4;

DEV_INLINE float mp_silu_f(float x) { return x / ((1.f + __expf(-x)) * 0.596f); }

DEV_INLINE unsigned short f2bf(float x) {
    unsigned u = __float_as_uint(x);
    unsigned r = (u + 0x7fffu + ((u >> 16) & 1u)) >> 16;
    return (unsigned short)r;
}
DEV_INLINE float bf2f(unsigned short u) { return __uint_as_float(((unsigned)u) << 16); }
DEV_INLINE float bflo(unsigned u) { return __uint_as_float(u << 16); }
DEV_INLINE float bfhi(unsigned u) { return __uint_as_float(u & 0xffff0000u); }

// ---------------------------------------------------------------------------
struct RsEnt { const float* w; float* o; int fan; int rowStart; };
struct RsTab { RsEnt e[23]; };

__global__ void rowscale_all_kernel(RsTab t) {
    int r = blockIdx.x;
    int ti = 0;
#pragma unroll
    for (int j = 1; j < 23; ++j)
        if (r >= t.e[j].rowStart) ti = j;
    const float* p = t.e[ti].w;
    int fan = t.e[ti].fan;
    int row = r - t.e[ti].rowStart;
    p += (size_t)row * fan;
    float s = 0.f;
    for (int i = threadIdx.x; i < fan; i += 256) { float v = p[i]; s += v * v; }
    __shared__ float red[256];
    red[threadIdx.x] = s;
    __syncthreads();
    for (int st = 128; st > 0; st >>= 1) {
        if (threadIdx.x < st) red[threadIdx.x] += red[threadIdx.x + st];
        __syncthreads();
    }
    if (threadIdx.x == 0) {
        float mean = red[0] / (float)fan;
        t.e[ti].o[row] = 1.f / sqrtf((mean + 1e-8f) * (float)fan);
    }
}

// ---- mid-conv weights: [e][oc][ic][3][3] f32 -> [e][icc6][tap9][oc192][ic32]
__global__ void wmid_cvt_kernel(const float* __restrict__ w, const float* __restrict__ wsc,
                                unsigned short* __restrict__ wt) {
    int i = blockIdx.x * 256 + threadIdx.x;
    if (i >= 4 * 9 * 192 * 192) return;
    int icl = i % 32;
    int t = i / 32;
    int oc = t % 192; t /= 192;
    int tap = t % 9; t /= 9;
    int icc = t % 6;
    int e = t / 6;
    int ic = icc * 32 + icl;
    wt[i] = f2bf(w[(((size_t)(e * 192 + oc) * 192 + ic) * 9) + tap] * wsc[e * 192 + oc]);
}

__global__ void femb_kernel(const float* __restrict__ tv, const float* __restrict__ fr,
                            const float* __restrict__ ph, float* __restrict__ femb) {
    int i = blockIdx.x * 256 + threadIdx.x;
    if (i >= 1024) return;
    int b = i >> 8, j = i & 255;
    femb[i] = 1.41421356237f * cosf(6.28318530717958647f * (tv[b] * fr[j] + ph[j]));
}

// ---- wave-per-output GEMV for small-M linears
template <int ACT, int HASRES>
__global__ void gemv_kernel(const float* __restrict__ A, const float* __restrict__ W,
                            const float* __restrict__ wsc, const float* __restrict__ res,
                            float osc, float* __restrict__ out, int N, int K) {
    int o = blockIdx.x * 4 + (threadIdx.x >> 6);
    int lane = threadIdx.x & 63;
    int m = o / N, n = o % N;
    const float* a = A + (size_t)m * K;
    const float* w = W + (size_t)n * K;
    float s = 0.f;
    for (int k = lane; k < K; k += 64) s += a[k] * w[k];
#pragma unroll
    for (int sh = 32; sh > 0; sh >>= 1) s += __shfl_xor(s, sh);
    if (lane == 0) {
        float val = s * wsc[n];
        if (ACT) val = mp_silu_f(val);
        if (HASRES) val = (val + res[(size_t)m * N + n]) * osc;
        out[(size_t)m * N + n] = val;
    }
}

// ---- two-source GEMV
__global__ void gemv2_kernel(const float* __restrict__ A1, const float* __restrict__ W1,
                             const float* __restrict__ s1v, int K1,
                             const float* __restrict__ A2, const float* __restrict__ W2,
                             const float* __restrict__ s2v, int K2,
                             float* __restrict__ out, int N) {
    int o = blockIdx.x * 4 + (threadIdx.x >> 6);
    int lane = threadIdx.x & 63;
    int m = o / N, n = o % N;
    const float* a1 = A1 + (size_t)m * K1;
    const float* w1 = W1 + (size_t)n * K1;
    float s1 = 0.f;
    for (int k = lane; k < K1; k += 64) s1 += a1[k] * w1[k];
    const float* a2 = A2 + (size_t)m * K2;
    const float* w2 = W2 + (size_t)n * K2;
    float s2 = 0.f;
    for (int k = lane; k < K2; k += 64) s2 += a2[k] * w2[k];
    float t = s1 * s1v[n] + s2 * s2v[n];
#pragma unroll
    for (int sh = 32; sh > 0; sh >>= 1) t += __shfl_xor(t, sh);
    if (lane == 0) out[(size_t)m * N + n] = t;
}

__global__ void scale_kernel(const float* __restrict__ temb, const float* __restrict__ w,
                             const float* __restrict__ wsc, const float* __restrict__ zeta,
                             float* __restrict__ scale2) {
    __shared__ float lg[8];
    int t = threadIdx.x;
    if (t < 8) {
        int b = t >> 1, o = t & 1;
        float s = 0.f;
        for (int k = 0; k < 512; ++k) s += temb[b * 512 + k] * w[o * 512 + k];
        lg[t] = s * wsc[o] / zeta[0];
    }
    __syncthreads();
    if (t < 4) {
        float a = lg[t * 2], b2 = lg[t * 2 + 1];
        float m = fmaxf(a, b2);
        float e0 = expf(a - m), e1 = expf(b2 - m);
        float inv = 2.f / (e0 + e1);
        scale2[t * 2] = e0 * inv;
        scale2[t * 2 + 1] = e1 * inv;
    }
}

__global__ void meanx_kernel(const float* __restrict__ x, float* __restrict__ mean_x) {
    int bc = blockIdx.x;
    float s = 0.f;
    for (int i = threadIdx.x; i < 4096; i += 256) s += x[bc * 4096 + i];
    __shared__ float red[256];
    red[threadIdx.x] = s;
    __syncthreads();
    for (int st = 128; st > 0; st >>= 1) {
        if (threadIdx.x < st) red[threadIdx.x] += red[threadIdx.x + st];
        __syncthreads();
    }
    if (threadIdx.x == 0) mean_x[bc] = red[0] * (1.f / 4096.f);
}

__global__ void router_kernel(const float* __restrict__ mean_x, const float* __restrict__ scale2,
                              const float* __restrict__ temb,
                              const float* __restrict__ wu, const float* __restrict__ su,
                              const float* __restrict__ wv, const float* __restrict__ sv,
                              const float* __restrict__ zeta,
                              int* __restrict__ eidx, float* __restrict__ gain,
                              float* __restrict__ rwv,
                              float* __restrict__ probs_out) {
    __shared__ float lg[2][4][4];
    int t = threadIdx.x;
    if (t < 32) {
        int r = t >> 4, b = (t >> 2) & 3, e = t & 3;
        const float* w = (r == 0) ? wu : wv;
        const float* sc = (r == 0) ? su : sv;
        float ps = scale2[b * 2 + (r == 0 ? 1 : 0)];
        float acc = 0.f;
        for (int c = 0; c < 4; ++c) acc += mean_x[b * 4 + c] * ps * w[e * 516 + c];
        for (int j = 0; j < 512; ++j) acc += temb[b * 512 + j] * w[e * 516 + 4 + j];
        lg[r][b][e] = acc * sc[e] / zeta[0];
    }
    __syncthreads();
    if (t < 8) {
        int r = t >> 2, b = t & 3;
        float p[4];
        float mx = -1e30f;
        for (int e = 0; e < 4; ++e) mx = fmaxf(mx, lg[r][b][e]);
        float sum = 0.f;
        for (int e = 0; e < 4; ++e) { p[e] = expf(lg[r][b][e] - mx); sum += p[e]; }
        for (int e = 0; e < 4; ++e) p[e] /= sum;
        int i1 = 0;
        for (int e = 1; e < 4; ++e) if (p[e] > p[i1]) i1 = e;
        int i2 = -1;
        for (int e = 0; e < 4; ++e) { if (e == i1) continue; if (i2 < 0 || p[e] > p[i2]) i2 = e; }
        float inv = 1.f / (p[i1] + p[i2]);
        if (r == 0) {
            eidx[b * 2] = i1; eidx[b * 2 + 1] = i2;
            gain[b * 2] = p[i1] * inv; gain[b * 2 + 1] = p[i2] * inv;
        } else {
            for (int e = 0; e < 4; ++e) rwv[b * 4 + e] = 0.f;
            rwv[b * 4 + i1] = p[i1] * inv;
            rwv[b * 4 + i2] = p[i2] * inv;
        }
        for (int e = 0; e < 4; ++e) probs_out[r * 16 + b * 4 + e] = p[e];
    }
}

__global__ void make_patch_kernel(const float* __restrict__ x, const float* __restrict__ scale2,
                                  float* __restrict__ in_unet, unsigned short* __restrict__ pt) {
    int i = blockIdx.x * 256 + threadIdx.x;
    if (i >= 65536) return;
    int b = i >> 14;
    int r = i & 16383;
    int s = r >> 8, f = r & 255;
    int c = f >> 6, py = (f >> 3) & 7, px = f & 7;
    int gy = s >> 3, gx = s & 7;
    int src = ((b * 4 + c) * 64 + gy * 8 + py) * 64 + gx * 8 + px;
    float v = x[src];
    pt[i] = f2bf(scale2[b * 2] * v);
    in_unet[src] = scale2[b * 2 + 1] * v;
}

__global__ void textp_kernel(const float* __restrict__ te, float* __restrict__ tp) {
    int i = blockIdx.x * 256 + threadIdx.x;
    if (i >= 3072) return;
    int b = i / 768, f = i % 768;
    float s = 0.f;
    for (int t = 0; t < 77; ++t) s += te[(size_t)(b * 77 + t) * 768 + f];
    tp[i] = s * (1.f / 77.f);
}

// ---------------------------------------------------------------------------
// conv_in (slots): NCHW f32 -> NHWC bf16 per slot. grid (16,24,8)
__global__ void conv_in_kernel(const float* __restrict__ in, const float* __restrict__ wbase,
                               const float* __restrict__ wscb, const float* __restrict__ tvec,
                               const int* __restrict__ eidx,
                               unsigned short* __restrict__ out) {
    int z = blockIdx.z, b = z >> 1;
    int e = eidx[z];
    const float* w = wbase + (size_t)e * 6912;
    const float* wsc = wscb + e * 192;
    const float* tmod = tvec + b * 768 + e * 192;
    int tileIdx = blockIdx.x;
    int ty0 = (tileIdx >> 2) * 16, tx0 = (tileIdx & 3) * 16;
    int oc0 = blockIdx.y * 8;
    int lty = threadIdx.x >> 4, ltx = threadIdx.x & 15;
    int y = ty0 + lty, x = tx0 + ltx;
    __shared__ float tile[4][18][18];
    for (int i = threadIdx.x; i < 4 * 18 * 18; i += 256) {
        int ic = i / 324, rr = (i / 18) % 18, cc = i % 18;
        int gy = ty0 - 1 + rr, gx = tx0 - 1 + cc;
        float v = 0.f;
        if (gy >= 0 && gy < 64 && gx >= 0 && gx < 64)
            v = in[((b * 4 + ic) * 64 + gy) * 64 + gx];
        tile[ic][rr][cc] = v;
    }
    __syncthreads();
    float win[4][9];
#pragma unroll
    for (int ic = 0; ic < 4; ++ic)
#pragma unroll
        for (int ky = 0; ky < 3; ++ky)
#pragma unroll
            for (int kx = 0; kx < 3; ++kx)
                win[ic][ky * 3 + kx] = tile[ic][lty + ky][ltx + kx];
#pragma unroll
    for (int o = 0; o < 8; ++o) {
        int oc = oc0 + o;
        float acc = 0.f;
#pragma unroll
        for (int ic = 0; ic < 4; ++ic) {
            const float* wp = w + (size_t)(oc * 4 + ic) * 9;
#pragma unroll
            for (int kk = 0; kk < 9; ++kk) acc += wp[kk] * win[ic][kk];
        }
        float val = acc * wsc[oc] * (1.f + tmod[oc]);
        val = mp_silu_f(val);
        out[((z * 64 + y) * 64 + x) * 192 + oc] = f2bf(val);
    }
}

// ---------------------------------------------------------------------------
// mid conv (r11-v2 + XCD swizzle): 1D grid 768; slot = id%8 (per-XCD L2
// locality for weights+A under round-robin dispatch; heuristic only).
// decode: slot = id%8, j = id/8, oc-tile = j/32, y-tile = j%32.
__global__ __launch_bounds__(256) void conv_mid_mfma(
    const unsigned short* __restrict__ in, const unsigned short* __restrict__ wtbase,
    const int* __restrict__ eidx,
    unsigned short* __restrict__ out) {
    int id = blockIdx.x;
    int z = id & 7;
    int j = id >> 3;
    int y0 = (j & 31) * 2;
    int oc0 = (j >> 5) * 64;
    int e = eidx[z];
    const unsigned short* wt = wtbase + (size_t)e * 331776;
    int wid = threadIdx.x >> 6, lane = threadIdx.x & 63;
    int wm = wid >> 1, wn = wid & 1;
    int l15 = lane & 15, lq = lane >> 4;

    __shared__ unsigned short Alds[4 * 66 * 72];
    f32x4 acc[4][2];
#pragma unroll
    for (int g = 0; g < 4; ++g)
#pragma unroll
        for (int f = 0; f < 2; ++f) acc[g][f] = (f32x4){0.f, 0.f, 0.f, 0.f};

    int ocA = oc0 + wn * 32 + l15;
    int ocB = ocA + 16;

    for (int icc = 0; icc < 6; ++icc) {
        const unsigned short* wicc = wt + (size_t)icc * (9 * 192 * 32);
        bf16x8 wreg[9][2];
#pragma unroll
        for (int tap = 0; tap < 9; ++tap) {
            wreg[tap][0] = *(const bf16x8*)&wicc[(tap * 192 + ocA) * 32 + 8 * lq];
            wreg[tap][1] = *(const bf16x8*)&wicc[(tap * 192 + ocB) * 32 + 8 * lq];
        }
        int ic0 = icc * 32;
        for (int i = threadIdx.x; i < 1056; i += 256) {
            int q = i & 3;
            int xx = (i >> 2) % 66;
            int r = (i >> 2) / 66;
            int y = y0 - 1 + r, xg = xx - 1;
            uint4 val = {0u, 0u, 0u, 0u};
            if (y >= 0 && y < 64 && xg >= 0 && xg < 64)
                val = *(const uint4*)&in[((z * 64 + y) * 64 + xg) * 192 + ic0 + q * 8];
            *(uint4*)&Alds[(r * 66 + xx) * 72 + q * 8] = val;
        }
        __syncthreads();
#pragma unroll
        for (int tap = 0; tap < 9; ++tap) {
            int ky = tap / 3, kx = tap % 3;
            int r = wm + ky;
#pragma unroll
            for (int g = 0; g < 4; ++g) {
                int xx = g * 16 + l15 + kx;
                bf16x8 afr = *(const bf16x8*)&Alds[(r * 66 + xx) * 72 + 8 * lq];
                acc[g][0] = __builtin_amdgcn_mfma_f32_16x16x32_bf16(afr, wreg[tap][0], acc[g][0], 0, 0, 0);
                acc[g][1] = __builtin_amdgcn_mfma_f32_16x16x32_bf16(afr, wreg[tap][1], acc[g][1], 0, 0, 0);
            }
        }
        __syncthreads();
    }
    int orow = y0 + wm;
#pragma unroll
    for (int g = 0; g < 4; ++g)
#pragma unroll
        for (int fn = 0; fn < 2; ++fn) {
            int oc = oc0 + wn * 32 + fn * 16 + l15;
#pragma unroll
            for (int r2 = 0; r2 < 4; ++r2) {
                int px = g * 16 + lq * 4 + r2;
                float v = mp_silu_f(acc[g][fn][r2]);
                out[((z * 64 + orow) * 64 + px) * 192 + oc] = f2bf(v);
            }
        }
}

// ---------------------------------------------------------------------------
// conv_out (slots, split-K): grid (16 tiles, 8 kchunks, 8 slots), atomicAdd.
__global__ __launch_bounds__(256) void conv_out_kernel(
    const unsigned short* __restrict__ in, const float* __restrict__ wbase,
    const float* __restrict__ wscb, const int* __restrict__ eidx,
    const float* __restrict__ gain, float* __restrict__ out) {
    int z = blockIdx.z, b = z >> 1;
    int e = eidx[z];
    float g = gain[z];
    const float* w = wbase + (size_t)e * 6912;
    const float* wsc = wscb + e * 4;
    int c0 = blockIdx.y * 24;
    int tileIdx = blockIdx.x;
    int ty0 = (tileIdx >> 2) * 16, tx0 = (tileIdx & 3) * 16;
    int lty = threadIdx.x >> 4, ltx = threadIdx.x & 15;
    int y = ty0 + lty, x = tx0 + ltx;
    __shared__ float tile[24][18][18];
    for (int i = threadIdx.x; i < 972; i += 256) {
        int q = i % 3, cell = i / 3;
        int rr = cell / 18, cc = cell % 18;
        int gy = ty0 - 1 + rr, gx = tx0 - 1 + cc;
        uint4 raw = {0u, 0u, 0u, 0u};
        if (gy >= 0 && gy < 64 && gx >= 0 && gx < 64)
            raw = *(const uint4*)&in[((z * 64 + gy) * 64 + gx) * 192 + c0 + q * 8];
        int icb = q * 8;
        tile[icb + 0][rr][cc] = bflo(raw.x);
        tile[icb + 1][rr][cc] = bfhi(raw.x);
        tile[icb + 2][rr][cc] = bflo(raw.y);
        tile[icb + 3][rr][cc] = bfhi(raw.y);
        tile[icb + 4][rr][cc] = bflo(raw.z);
        tile[icb + 5][rr][cc] = bfhi(raw.z);
        tile[icb + 6][rr][cc] = bflo(raw.w);
        tile[icb + 7][rr][cc] = bfhi(raw.w);
    }
    __syncthreads();
    float acc[4] = {0.f, 0.f, 0.f, 0.f};
#pragma unroll
    for (int ic = 0; ic < 24; ++ic) {
        float win[9];
#pragma unroll
        for (int ky = 0; ky < 3; ++ky)
#pragma unroll
            for (int kx = 0; kx < 3; ++kx)
                win[ky * 3 + kx] = tile[ic][lty + ky][ltx + kx];
#pragma unroll
        for (int o = 0; o < 4; ++o) {
            const float* wp = w + (size_t)(o * 192 + c0 + ic) * 9;
#pragma unroll
            for (int kk = 0; kk < 9; ++kk) acc[o] += wp[kk] * win[kk];
        }
    }
#pragma unroll
    for (int o = 0; o < 4; ++o)
        atomicAdd(&out[((b * 4 + o) * 64 + y) * 64 + x], g * acc[o] * wsc[o]);
}

// ---------------------------------------------------------------------------
// bf16 MFMA linear: grid (M/64, N/64, E), software pipelined.
template <int ACT>
__global__ __launch_bounds__(256) void mfma_linear_kernel(
    const unsigned short* __restrict__ A, int aE,
    const float* __restrict__ W, int wE,
    const float* __restrict__ wsc, int wscE,
    const float* __restrict__ pos, int posE,
    const float* __restrict__ cond, int condRow, int condE,
    const unsigned short* __restrict__ res, int resE, float outscale,
    const float* __restrict__ gate,
    unsigned short* __restrict__ outp, int outE,
    int M, int N, int K) {
    int e = blockIdx.z;
    int bm = blockIdx.x * 64, bn = blockIdx.y * 64;
    if (gate && gate[(bm >> 6) * 4 + e] == 0.f) return;
    A += (size_t)e * aE;
    W += (size_t)e * wE;
    wsc += (size_t)e * wscE;
    if (pos) pos += (size_t)e * posE;
    if (cond) cond += (size_t)e * condE;
    if (res) res += (size_t)e * resE;
    outp += (size_t)e * outE;

    int tid = threadIdx.x;
    int wid = tid >> 6, lane = tid & 63;
    int wm = wid >> 1, wn = wid & 1;
    int l15 = lane & 15, lq = lane >> 4;
    __shared__ unsigned short Al[64 * 72];
    __shared__ unsigned short Wl[64 * 72];
    f32x4 acc[2][2];
#pragma unroll
    for (int mf = 0; mf < 2; ++mf)
#pragma unroll
        for (int nf = 0; nf < 2; ++nf) acc[mf][nf] = (f32x4){0.f, 0.f, 0.f, 0.f};

    int ar = tid >> 3, ac = (tid & 7) * 8;
    int wr = tid >> 4, wc = (tid & 15) * 4;
    uint4 pa0, pa1;
    float4 pw0, pw1, pw2, pw3;

    auto gload = [&](int k0) {
        pa0 = *(const uint4*)&A[(size_t)(bm + ar) * K + k0 + ac];
        pa1 = *(const uint4*)&A[(size_t)(bm + ar + 32) * K + k0 + ac];
        pw0 = *(const float4*)&W[(size_t)(bn + wr) * K + k0 + wc];
        pw1 = *(const float4*)&W[(size_t)(bn + wr + 16) * K + k0 + wc];
        pw2 = *(const float4*)&W[(size_t)(bn + wr + 32) * K + k0 + wc];
        pw3 = *(const float4*)&W[(size_t)(bn + wr + 48) * K + k0 + wc];
    };
    auto sstore = [&]() {
        *(uint4*)&Al[ar * 72 + ac] = pa0;
        *(uint4*)&Al[(ar + 32) * 72 + ac] = pa1;
        ushort4 s;
        s.x = f2bf(pw0.x); s.y = f2bf(pw0.y); s.z = f2bf(pw0.z); s.w = f2bf(pw0.w);
        *(ushort4*)&Wl[wr * 72 + wc] = s;
        s.x = f2bf(pw1.x); s.y = f2bf(pw1.y); s.z = f2bf(pw1.z); s.w = f2bf(pw1.w);
        *(ushort4*)&Wl[(wr + 16) * 72 + wc] = s;
        s.x = f2bf(pw2.x); s.y = f2bf(pw2.y); s.z = f2bf(pw2.z); s.w = f2bf(pw2.w);
        *(ushort4*)&Wl[(wr + 32) * 72 + wc] = s;
        s.x = f2bf(pw3.x); s.y = f2bf(pw3.y); s.z = f2bf(pw3.z); s.w = f2bf(pw3.w);
        *(ushort4*)&Wl[(wr + 48) * 72 + wc] = s;
    };

    int nk = K >> 6;
    gload(0);
    for (int kk = 0; kk < nk; ++kk) {
        sstore();
        __syncthreads();
        if (kk + 1 < nk) gload((kk + 1) << 6);
#pragma unroll
        for (int ks = 0; ks < 2; ++ks) {
            bf16x8 af[2], wf[2];
#pragma unroll
            for (int mf = 0; mf < 2; ++mf)
                af[mf] = *(const bf16x8*)&Al[(wm * 32 + mf * 16 + l15) * 72 + ks * 32 + lq * 8];
#pragma unroll
            for (int nf = 0; nf < 2; ++nf)
                wf[nf] = *(const bf16x8*)&Wl[(wn * 32 + nf * 16 + l15) * 72 + ks * 32 + lq * 8];
#pragma unroll
            for (int mf = 0; mf < 2; ++mf)
#pragma unroll
                for (int nf = 0; nf < 2; ++nf)
                    acc[mf][nf] = __builtin_amdgcn_mfma_f32_16x16x32_bf16(af[mf], wf[nf], acc[mf][nf], 0, 0, 0);
        }
        __syncthreads();
    }
#pragma unroll
    for (int mf = 0; mf < 2; ++mf)
#pragma unroll
        for (int nf = 0; nf < 2; ++nf) {
            int n = bn + wn * 32 + nf * 16 + l15;
            float ws = wsc[n];
#pragma unroll
            for (int r = 0; r < 4; ++r) {
                int m = bm + wm * 32 + mf * 16 + lq * 4 + r;
                float val = acc[mf][nf][r] * ws;
                if (pos) val += pos[(m & 63) * N + n];
                if (cond) val *= (1.f + cond[(m >> 6) * condRow + n]);
                if (ACT) val = mp_silu_f(val);
                if (res) val = (val + bf2f(res[(size_t)m * N + n])) * outscale;
                outp[(size_t)m * N + n] = f2bf(val);
            }
        }
}

// ---- ViT self-attention v2
__global__ __launch_bounds__(256) void vit_attn_kernel(
    const unsigned short* __restrict__ qkv_base,
    const float* __restrict__ rwv,
    unsigned short* __restrict__ out_base) {
    int e = blockIdx.x >> 5, b = (blockIdx.x >> 3) & 3, h = blockIdx.x & 7;
    if (rwv[b * 4 + e] == 0.f) return;
    const unsigned short* qkv = qkv_base + (size_t)e * 393216;
    unsigned short* out = out_base + (size_t)e * 131072;
    __shared__ float ks[64][68], vs[64][68];
    int tid = threadIdx.x;
    for (int i = tid; i < 512; i += 256) {
        int j = i >> 3, c = (i & 7) * 8;
        const unsigned short* kp = &qkv[(size_t)(b * 64 + j) * 1536 + 512 + h * 64 + c];
        uint4 kr = *(const uint4*)kp;
        uint4 vr = *(const uint4*)(kp + 512);
        float* kd = &ks[j][c];
        float* vd = &vs[j][c];
        kd[0] = bflo(kr.x); kd[1] = bfhi(kr.x); kd[2] = bflo(kr.y); kd[3] = bfhi(kr.y);
        kd[4] = bflo(kr.z); kd[5] = bfhi(kr.z); kd[6] = bflo(kr.w); kd[7] = bfhi(kr.w);
        vd[0] = bflo(vr.x); vd[1] = bfhi(vr.x); vd[2] = bflo(vr.y); vd[3] = bfhi(vr.y);
        vd[4] = bflo(vr.z); vd[5] = bfhi(vr.z); vd[6] = bflo(vr.w); vd[7] = bfhi(vr.w);
    }
    int qr = tid >> 2, kq = tid & 3;
    float qreg[64];
#pragma unroll
    for (int c8 = 0; c8 < 8; ++c8) {
        uint4 q4 = *(const uint4*)&qkv[(size_t)(b * 64 + qr) * 1536 + h * 64 + c8 * 8];
        qreg[c8 * 8 + 0] = bflo(q4.x); qreg[c8 * 8 + 1] = bfhi(q4.x);
        qreg[c8 * 8 + 2] = bflo(q4.y); qreg[c8 * 8 + 3] = bfhi(q4.y);
        qreg[c8 * 8 + 4] = bflo(q4.z); qreg[c8 * 8 + 5] = bfhi(q4.z);
        qreg[c8 * 8 + 6] = bflo(q4.w); qreg[c8 * 8 + 7] = bfhi(q4.w);
    }
    __syncthreads();
    float sc[16];
    float m = -1e30f;
    int j0 = kq * 16;
#pragma unroll
    for (int jj = 0; jj < 16; ++jj) {
        int j = j0 + jj;
        float s = 0.f;
#pragma unroll
        for (int d4 = 0; d4 < 16; ++d4) {
            float4 kk = *(const float4*)&ks[j][d4 * 4];
            s += qreg[d4 * 4] * kk.x + qreg[d4 * 4 + 1] * kk.y +
                 qreg[d4 * 4 + 2] * kk.z + qreg[d4 * 4 + 3] * kk.w;
        }
        s *= 0.125f;
        sc[jj] = s;
        m = fmaxf(m, s);
    }
    float l = 0.f;
    float4 acc4[16];
#pragma unroll
    for (int d4 = 0; d4 < 16; ++d4) acc4[d4] = (float4){0.f, 0.f, 0.f, 0.f};
#pragma unroll
    for (int jj = 0; jj < 16; ++jj) {
        int j = j0 + jj;
        float ee = __expf(sc[jj] - m);
        l += ee;
#pragma unroll
        for (int d4 = 0; d4 < 16; ++d4) {
            float4 vv = *(const float4*)&vs[j][d4 * 4];
            acc4[d4].x += ee * vv.x; acc4[d4].y += ee * vv.y;
            acc4[d4].z += ee * vv.z; acc4[d4].w += ee * vv.w;
        }
    }
#pragma unroll
    for (int mask = 1; mask <= 2; mask <<= 1) {
        float m2 = __shfl_xor(m, mask);
        float l2 = __shfl_xor(l, mask);
        float nm = fmaxf(m, m2);
        float c1 = __expf(m - nm), c2 = __expf(m2 - nm);
        l = l * c1 + l2 * c2;
#pragma unroll
        for (int d4 = 0; d4 < 16; ++d4) {
            acc4[d4].x = acc4[d4].x * c1 + __shfl_xor(acc4[d4].x, mask) * c2;
            acc4[d4].y = acc4[d4].y * c1 + __shfl_xor(acc4[d4].y, mask) * c2;
            acc4[d4].z = acc4[d4].z * c1 + __shfl_xor(acc4[d4].z, mask) * c2;
            acc4[d4].w = acc4[d4].w * c1 + __shfl_xor(acc4[d4].w, mask) * c2;
        }
        m = nm;
    }
    float inv = 1.f / l;
    unsigned short* op = &out[(size_t)(b * 64 + qr) * 512 + h * 64 + kq * 16];
#pragma unroll
    for (int d4 = 0; d4 < 4; ++d4) {
        int dd = kq * 4 + d4;
        ushort4 r;
        r.x = f2bf(acc4[dd].x * inv); r.y = f2bf(acc4[dd].y * inv);
        r.z = f2bf(acc4[dd].z * inv); r.w = f2bf(acc4[dd].w * inv);
        *(ushort4*)&op[d4 * 4] = r;
    }
}

__global__ void unpatch_scatter_kernel(const unsigned short* __restrict__ vout,
                                       const float* __restrict__ rwv,
                                       float* __restrict__ out_vit) {
    int i = blockIdx.x * 256 + threadIdx.x;
    if (i >= 65536) return;
    int b = i >> 14;
    int c = (i >> 12) & 3, y = (i >> 6) & 63, x = i & 63;
    int f = c * 64 + (y & 7) * 8 + (x & 7);
    int s = (y >> 3) * 8 + (x >> 3);
    int idx = (b * 64 + s) * 256 + f;
    float acc = 0.f;
#pragma unroll
    for (int e = 0; e < 4; ++e) {
        float g = rwv[b * 4 + e];
        if (g != 0.f) acc += g * bf2f(vout[e * 65536 + idx]);
    }
    out_vit[i] = acc;
}

// ---- ca_qkv + per-batch componentwise max|k|
__global__ void ca_qkv_kernel(const float* __restrict__ ou, const float* __restrict__ ov,
                              const float* __restrict__ wq, const float* __restrict__ sq,
                              const float* __restrict__ wk, const float* __restrict__ sk,
                              const float* __restrict__ wv, const float* __restrict__ sv,
                              float* __restrict__ q, float* __restrict__ kx, float* __restrict__ vx,
                              unsigned* __restrict__ kmax) {
    int i = blockIdx.x * 256 + threadIdx.x;
    if (i >= 16384) return;
    int b = i >> 12, t = i & 4095;
    float u[4], c[4];
#pragma unroll
    for (int cc = 0; cc < 4; ++cc) {
        u[cc] = ou[(size_t)(b * 4 + cc) * 4096 + t];
        c[cc] = ov[(size_t)(b * 4 + cc) * 4096 + t];
    }
    float km[4];
#pragma unroll
    for (int o = 0; o < 4; ++o) {
        float aq = 0.f, ak = 0.f, av = 0.f;
#pragma unroll
        for (int cc = 0; cc < 4; ++cc) {
            aq += wq[o * 4 + cc] * u[cc];
            ak += wk[o * 4 + cc] * c[cc];
            av += wv[o * 4 + cc] * c[cc];
        }
        float kvv = ak * sk[o];
        q[(size_t)(b * 4096 + t) * 4 + o] = aq * sq[o] * 0.5f;
        kx[(size_t)(b * 4096 + t) * 4 + o] = kvv;
        vx[(size_t)(b * 4096 + t) * 4 + o] = av * sv[o];
        km[o] = fabsf(kvv);
    }
#pragma unroll
    for (int sh = 32; sh > 0; sh >>= 1)
#pragma unroll
        for (int o = 0; o < 4; ++o) km[o] = fmaxf(km[o], __shfl_xor(km[o], sh));
    if ((threadIdx.x & 63) == 0)
#pragma unroll
        for (int o = 0; o < 4; ++o)
            atomicMax(&kmax[b * 4 + o], __float_as_uint(km[o]));
}

// ---- cross-attn v6: LDS-staged K/V, fixed-bound softmax.
__global__ __launch_bounds__(1024) void ca_attn_kernel(
    const float* __restrict__ q, const float* __restrict__ k,
    const float* __restrict__ v, const unsigned* __restrict__ kmax,
    float* __restrict__ o) {
    int b = blockIdx.x >> 6;
    int qg = blockIdx.x & 63;
    int lq = threadIdx.x & 63, wid = threadIdx.x >> 6;
    int qt = qg * 64 + lq;
    float4 qv = *(const float4*)&q[(size_t)(b * 4096 + qt) * 4];
    float M0 = __uint_as_float(kmax[b * 4 + 0]);
    float M1 = __uint_as_float(kmax[b * 4 + 1]);
    float M2 = __uint_as_float(kmax[b * 4 + 2]);
    float M3 = __uint_as_float(kmax[b * 4 + 3]);
    float nC = -(fabsf(qv.x) * M0 + fabsf(qv.y) * M1 + fabsf(qv.z) * M2 + fabsf(qv.w) * M3);
    const float4* kb = (const float4*)(k + (size_t)b * 16384);
    const float4* vb = (const float4*)(v + (size_t)b * 16384);

    __shared__ float4 kt[1024], vt[1024];
    int t = threadIdx.x;
    float l = 0.f, a0 = 0.f, a1 = 0.f, a2 = 0.f, a3 = 0.f;

    float4 pk = kb[t], pv = vb[t];
    int base = wid * 64;
    for (int r = 0; r < 4; ++r) {
        kt[t] = pk; vt[t] = pv;
        __syncthreads();
        if (r + 1 < 4) { pk = kb[(r + 1) * 1024 + t]; pv = vb[(r + 1) * 1024 + t]; }
#pragma unroll
        for (int jj = 0; jj < 64; jj += 4) {
            float4 kk0 = kt[base + jj],     kk1 = kt[base + jj + 1];
            float4 kk2 = kt[base + jj + 2], kk3 = kt[base + jj + 3];
            float4 vv0 = vt[base + jj],     vv1 = vt[base + jj + 1];
            float4 vv2 = vt[base + jj + 2], vv3 = vt[base + jj + 3];
            float s0 = fmaf(qv.w, kk0.w, fmaf(qv.z, kk0.z, fmaf(qv.y, kk0.y, fmaf(qv.x, kk0.x, nC))));
            float s1 = fmaf(qv.w, kk1.w, fmaf(qv.z, kk1.z, fmaf(qv.y, kk1.y, fmaf(qv.x, kk1.x, nC))));
            float s2 = fmaf(qv.w, kk2.w, fmaf(qv.z, kk2.z, fmaf(qv.y, kk2.y, fmaf(qv.x, kk2.x, nC))));
            float s3 = fmaf(qv.w, kk3.w, fmaf(qv.z, kk3.z, fmaf(qv.y, kk3.y, fmaf(qv.x, kk3.x, nC))));
            float e0 = __expf(s0), e1 = __expf(s1), e2 = __expf(s2), e3 = __expf(s3);
            l += (e0 + e1) + (e2 + e3);
            a0 = fmaf(e0, vv0.x, a0); a1 = fmaf(e0, vv0.y, a1);
            a2 = fmaf(e0, vv0.z, a2); a3 = fmaf(e0, vv0.w, a3);
            a0 = fmaf(e1, vv1.x, a0); a1 = fmaf(e1, vv1.y, a1);
            a2 = fmaf(e1, vv1.z, a2); a3 = fmaf(e1, vv1.w, a3);
            a0 = fmaf(e2, vv2.x, a0); a1 = fmaf(e2, vv2.y, a1);
            a2 = fmaf(e2, vv2.z, a2); a3 = fmaf(e2, vv2.w, a3);
            a0 = fmaf(e3, vv3.x, a0); a1 = fmaf(e3, vv3.y, a1);
            a2 = fmaf(e3, vv3.z, a2); a3 = fmaf(e3, vv3.w, a3);
        }
        __syncthreads();
    }
    __shared__ float red[16][64][5];
    red[wid][lq][0] = l;
    red[wid][lq][1] = a0; red[wid][lq][2] = a1;
    red[wid][lq][3] = a2; red[wid][lq][4] = a3;
    __syncthreads();
    if (threadIdx.x < 64) {
        int qq = threadIdx.x;
        float ll = 0.f, b0 = 0.f, b1 = 0.f, b2 = 0.f, b3 = 0.f;
#pragma unroll
        for (int s2 = 0; s2 < 16; ++s2) {
            ll += red[s2][qq][0];
            b0 += red[s2][qq][1];
            b1 += red[s2][qq][2];
            b2 += red[s2][qq][3];
            b3 += red[s2][qq][4];
        }
        float inv = 1.f / ll;
        float* op = &o[(size_t)(b * 4096 + qg * 64 + qq) * 4];
        op[0] = b0 * inv; op[1] = b1 * inv; op[2] = b2 * inv; op[3] = b3 * inv;
    }
}

// ---- fused: out-proj + balanced blend + gated combine -> d_out
__global__ void ca_final_kernel(const float* __restrict__ ao, const float* __restrict__ ou,
                                const float* __restrict__ wo, const float* __restrict__ so,
                                const float* __restrict__ gw1, const float* __restrict__ s1,
                                const float* __restrict__ gw2, const float* __restrict__ s2,
                                float* __restrict__ out) {
    int i = blockIdx.x * 256 + threadIdx.x;
    if (i >= 16384) return;
    int b = i >> 12, t = i & 4095;
    float oo[4], u[4], a[4];
#pragma unroll
    for (int j = 0; j < 4; ++j) oo[j] = ao[(size_t)(b * 4096 + t) * 4 + j];
#pragma unroll
    for (int c = 0; c < 4; ++c) u[c] = ou[(size_t)(b * 4 + c) * 4096 + t];
    const float binv = 1.21267812518f;
#pragma unroll
    for (int c = 0; c < 4; ++c) {
        float s = 0.f;
#pragma unroll
        for (int j = 0; j < 4; ++j) s += wo[c * 4 + j] * oo[j];
        s *= so[c];
        a[c] = (0.2f * u[c] + 0.8f * s) * binv;
    }
    float mvec[4];
#pragma unroll
    for (int o = 0; o < 4; ++o) {
        float s = 0.f;
#pragma unroll
        for (int c = 0; c < 4; ++c) s += gw1[o * 8 + c] * u[c] + gw1[o * 8 + 4 + c] * a[c];
        mvec[o] = mp_silu_f(s * s1[o]);
    }
    float g0 = 0.f, g1 = 0.f;
#pragma unroll
    for (int o = 0; o < 4; ++o) { g0 += gw2[o] * mvec[o]; g1 += gw2[4 + o] * mvec[o]; }
    g0 *= s2[0]; g1 *= s2[1];
    float mx = fmaxf(g0, g1);
    float e0 = expf(g0 - mx), e1 = expf(g1 - mx);
    float invd = 1.f / (e0 + e1);
    g0 = e0 * invd; g1 = e1 * invd;
#pragma unroll
    for (int c = 0; c < 4; ++c)
        out[(size_t)(b * 4 + c) * 4096 + t] = g0 * u[c] + g1 * a[c];
}

// ---------------------------------------------------------------------------
extern "C" void kernel_launch(void* const* d_in, const int* in_sizes, int n_in,
                              void* d_out, int out_size, void* d_ws, size_t ws_size,
                              hipStream_t stream) {
    (void)in_sizes; (void)n_in; (void)out_size; (void)ws_size;

    const float* x        = (const float*)d_in[0];
    const float* time_vec = (const float*)d_in[1];
    const float* text_emb = (const float*)d_in[2];
    const float* zeta     = (const float*)d_in[5];
    const float* f_freq   = (const float*)d_in[6];
    const float* f_phase  = (const float*)d_in[7];
    const float* w_f1     = (const float*)d_in[8];
    const float* w_f2     = (const float*)d_in[9];
    const float* w_scale  = (const float*)d_in[10];
    const float* w_ru     = (const float*)d_in[11];
    const float* w_rv     = (const float*)d_in[12];
    const float* uw_in    = (const float*)d_in[13];
    const float* uw_time  = (const float*)d_in[14];
    const float* uw_mid   = (const float*)d_in[15];
    const float* uw_out   = (const float*)d_in[16];
    const float* vw_patch = (const float*)d_in[17];
    const float* v_pos    = (const float*)d_in[18];
    const float* vw_qkv   = (const float*)d_in[19];
    const float* vw_proj  = (const float*)d_in[20];
    const float* vw_time  = (const float*)d_in[21];
    const float* vw_text  = (const float*)d_in[22];
    const float* vw_mlp1  = (const float*)d_in[23];
    const float* vw_mlp2  = (const float*)d_in[24];
    const float* vw_unp   = (const float*)d_in[25];
    const float* ca_wq    = (const float*)d_in[26];
    const float* ca_wk    = (const float*)d_in[27];
    const float* ca_wv    = (const float*)d_in[28];
    const float* ca_wo    = (const float*)d_in[29];
    const float* gw1      = (const float*)d_in[30];
    const float* gw2      = (const float*)d_in[31];

    float* out = (float*)d_out;

    float* Wp = (float*)d_ws;
    size_t off = 0;
    auto alloc = [&](size_t n) { float* p = Wp + off; off += (n + 3) & ~(size_t)3; return p; };

    float* s_wf1   = alloc(1024);
    float* s_wf2   = alloc(512);
    float* s_wsc   = alloc(2);
    float* s_wru   = alloc(4);
    float* s_wrv   = alloc(4);
    float* s_uwin  = alloc(768);
    float* s_uwt   = alloc(768);
    float* s_uwm   = alloc(768);
    float* s_uwo   = alloc(16);
    float* s_vwp   = alloc(2048);
    float* s_vwqkv = alloc(6144);
    float* s_vwpr  = alloc(2048);
    float* s_vwti  = alloc(2048);
    float* s_vwte  = alloc(2048);
    float* s_vwm1  = alloc(8192);
    float* s_vwm2  = alloc(2048);
    float* s_vwun  = alloc(1024);
    float* s_cawq  = alloc(4);
    float* s_cawk  = alloc(4);
    float* s_cawv  = alloc(4);
    float* s_cawo  = alloc(4);
    float* s_gw1   = alloc(4);
    float* s_gw2   = alloc(2);

    float* femb    = alloc(1024);
    float* h1      = alloc(4096);
    float* temb    = alloc(2048);
    float* scale2  = alloc(8);
    float* mean_x  = alloc(16);
    int*   eidx    = (int*)alloc(8);
    float* gain    = alloc(8);
    float* rwv     = alloc(16);
    float* textp   = alloc(3072);
    float* tvec    = alloc(3072);
    unsigned short* patchtok = (unsigned short*)alloc(32768);
    float* in_unet = alloc(65536);
    float* out_unet= alloc(65536);
    float* out_vit = alloc(65536);
    float* vcond   = alloc(8192);
    unsigned* kmax = (unsigned*)alloc(16);
    unsigned short* wtmid = (unsigned short*)alloc(663552);

    float* region  = alloc(6291456);
    unsigned short* bufA = (unsigned short*)region;
    unsigned short* bufB = (unsigned short*)(region + 3145728);
    unsigned short* us   = (unsigned short*)region;
    unsigned short* vtok  = us + 0;
    unsigned short* vqkv  = us + 524288;
    unsigned short* vao   = us + 2097152;
    unsigned short* vtok2 = us + 2621440;
    unsigned short* vhid  = us + 3145728;
    unsigned short* vtok3 = us + 5242880;
    unsigned short* vout  = us + 5767168;

    float* caq     = alloc(65536);
    float* cak     = alloc(65536);
    float* cav     = alloc(65536);
    float* cao     = alloc(65536);

    // ---- merged rowscale
    RsTab tab;
    int rowCounts[23] = {1024, 512, 2, 4, 4, 768, 768, 768, 16, 2048, 6144, 2048,
                         2048, 2048, 8192, 2048, 1024, 4, 4, 4, 4, 4, 2};
    const float* srcs[23] = {w_f1, w_f2, w_scale, w_ru, w_rv, uw_in, uw_time, uw_mid, uw_out,
                             vw_patch, vw_qkv, vw_proj, vw_time, vw_text, vw_mlp1, vw_mlp2,
                             vw_unp, ca_wq, ca_wk, ca_wv, ca_wo, gw1, gw2};
    float* dsts[23] = {s_wf1, s_wf2, s_wsc, s_wru, s_wrv, s_uwin, s_uwt, s_uwm, s_uwo,
                       s_vwp, s_vwqkv, s_vwpr, s_vwti, s_vwte, s_vwm1, s_vwm2,
                       s_vwun, s_cawq, s_cawk, s_cawv, s_cawo, s_gw1, s_gw2};
    int fans[23] = {256, 1024, 512, 516, 516, 36, 512, 1728, 1728, 256, 512, 512,
                    512, 768, 512, 2048, 512, 4, 4, 4, 4, 8, 4};
    int cum = 0;
    for (int i = 0; i < 23; ++i) {
        tab.e[i].w = srcs[i]; tab.e[i].o = dsts[i];
        tab.e[i].fan = fans[i]; tab.e[i].rowStart = cum;
        cum += rowCounts[i];
    }
    rowscale_all_kernel<<<dim3(cum), dim3(256), 0, stream>>>(tab);
    wmid_cvt_kernel<<<dim3((1327104 + 255) / 256), dim3(256), 0, stream>>>(uw_mid, s_uwm, wtmid);

    auto gemv = [&](int ACT, int HASRES, const float* A, const float* W2, const float* wsc,
                    const float* res, float osc, float* o, int M, int N, int K) {
        dim3 g(M * N / 4);
        if (ACT)
            gemv_kernel<1, 0><<<g, 256, 0, stream>>>(A, W2, wsc, res, osc, o, N, K);
        else if (HASRES)
            gemv_kernel<0, 1><<<g, 256, 0, stream>>>(A, W2, wsc, res, osc, o, N, K);
        else
            gemv_kernel<0, 0><<<g, 256, 0, stream>>>(A, W2, wsc, res, osc, o, N, K);
    };

    // ---- time embedding chain
    femb_kernel<<<dim3(4), dim3(256), 0, stream>>>(time_vec, f_freq, f_phase, femb);
    gemv(1, 0, femb, w_f1, s_wf1, nullptr, 1.f, h1, 4, 1024, 256);
    gemv(0, 0, h1, w_f2, s_wf2, nullptr, 1.f, temb, 4, 512, 1024);

    scale_kernel<<<dim3(1), dim3(64), 0, stream>>>(temb, w_scale, s_wsc, zeta, scale2);
    meanx_kernel<<<dim3(16), dim3(256), 0, stream>>>(x, mean_x);
    router_kernel<<<dim3(1), dim3(64), 0, stream>>>(mean_x, scale2, temb, w_ru, s_wru, w_rv, s_wrv,
                                                    zeta, eidx, gain, rwv, out + 65536);
    make_patch_kernel<<<dim3(256), dim3(256), 0, stream>>>(x, scale2, in_unet, patchtok);
    textp_kernel<<<dim3(12), dim3(256), 0, stream>>>(text_emb, textp);

    gemv(0, 0, temb, uw_time, s_uwt, nullptr, 1.f, tvec, 4, 768, 512);

    hipMemsetAsync(out_unet, 0, 65536 * sizeof(float), stream);
    hipMemsetAsync(kmax, 0, 16 * sizeof(unsigned), stream);

    // ---- UNet conv chain, slot-compacted
    conv_in_kernel<<<dim3(16, 24, 8), dim3(256), 0, stream>>>(
        in_unet, uw_in, s_uwin, tvec, eidx, bufA);
    conv_mid_mfma<<<dim3(768), dim3(256), 0, stream>>>(
        bufA, wtmid, eidx, bufB);
    conv_out_kernel<<<dim3(16, 8, 8), dim3(256), 0, stream>>>(
        bufB, uw_out, s_uwo, eidx, gain, out_unet);

    // ---- ViT cond vectors
    gemv2_kernel<<<dim3(2048), dim3(256), 0, stream>>>(temb, vw_time, s_vwti, 512,
                                                       textp, vw_text, s_vwte, 768,
                                                       vcond, 2048);

    auto mlin = [&](int ACT, const unsigned short* A, int aE, const float* W2, int wE2,
                    const float* wsc, int wscE, const float* pos, int posE,
                    const float* cond, int condRow, int condE,
                    const unsigned short* res, int resE, float osc,
                    const float* gate, unsigned short* o, int outE, int M, int N, int K) {
        dim3 g(M / 64, N / 64, 4);
        if (ACT)
            mfma_linear_kernel<1><<<g, 256, 0, stream>>>(A, aE, W2, wE2, wsc, wscE, pos, posE,
                                                         cond, condRow, condE, res, resE, osc,
                                                         gate, o, outE, M, N, K);
        else
            mfma_linear_kernel<0><<<g, 256, 0, stream>>>(A, aE, W2, wE2, wsc, wscE, pos, posE,
                                                         cond, condRow, condE, res, resE, osc,
                                                         gate, o, outE, M, N, K);
    };

    // ---- ViT expert stack
    mlin(0, patchtok, 0, vw_patch, 131072, s_vwp, 512, v_pos, 32768,
         vcond, 2048, 512, nullptr, 0, 1.f, rwv, vtok, 131072, 256, 512, 256);
    mlin(0, vtok, 131072, vw_qkv, 786432, s_vwqkv, 1536, nullptr, 0,
         nullptr, 0, 0, nullptr, 0, 1.f, rwv, vqkv, 393216, 256, 1536, 512);
    vit_attn_kernel<<<dim3(128), dim3(256), 0, stream>>>(vqkv, rwv, vao);
    mlin(0, vao, 131072, vw_proj, 262144, s_vwpr, 512, nullptr, 0,
         nullptr, 0, 0, vtok, 131072, 0.70710678f, rwv, vtok2, 131072, 256, 512, 512);
    mlin(1, vtok2, 131072, vw_mlp1, 1048576, s_vwm1, 2048, nullptr, 0,
         nullptr, 0, 0, nullptr, 0, 1.f, rwv, vhid, 524288, 256, 2048, 512);
    mlin(0, vhid, 524288, vw_mlp2, 1048576, s_vwm2, 512, nullptr, 0,
         nullptr, 0, 0, vtok2, 131072, 0.70710678f, rwv, vtok3, 131072, 256, 512, 2048);
    mlin(0, vtok3, 131072, vw_unp, 131072, s_vwun, 256, nullptr, 0,
         nullptr, 0, 0, nullptr, 0, 1.f, rwv, vout, 65536, 256, 256, 512);
    unpatch_scatter_kernel<<<dim3(256), dim3(256), 0, stream>>>(vout, rwv, out_vit);

    // ---- cross attention + fused tail
    ca_qkv_kernel<<<dim3(64), dim3(256), 0, stream>>>(out_unet, out_vit, ca_wq, s_cawq,
                                                      ca_wk, s_cawk, ca_wv, s_cawv,
                                                      caq, cak, cav, kmax);
    ca_attn_kernel<<<dim3(256), dim3(1024), 0, stream>>>(caq, cak, cav, kmax, cao);
    ca_final_kernel<<<dim3(64), dim3(256), 0, stream>>>(cao, out_unet, ca_wo, s_cawo,
                                                        gw1, s_gw1, gw2, s_gw2, out);
}